// Round 23
// baseline (68.529 us; speedup 1.0000x reference)
//
#include <hip/hip_runtime.h>
#include <hip/hip_bf16.h>

#define B_ 8
#define T_ 2048
#define C_ 1024
#define H_ 64

typedef __bf16 bf16x8 __attribute__((ext_vector_type(8)));
typedef float f32x4 __attribute__((ext_vector_type(4)));

__device__ __forceinline__ unsigned short f2bf(float f) {
    union { float f; unsigned u; } v; v.f = f;
    unsigned u = v.u;
    u += 0x7fffu + ((u >> 16) & 1u);   // round-to-nearest-even
    return (unsigned short)(u >> 16);
}
__device__ __forceinline__ float bf2f(unsigned short u) {
    union { unsigned u; float f; } v; v.u = ((unsigned)u) << 16; return v.f;
}

#define GLOAD16(g, l) __builtin_amdgcn_global_load_lds( \
    (const __attribute__((address_space(1))) void*)(g), \
    (__attribute__((address_space(3))) void*)(l), 16, 0, 0)

#define MFMA16(a, b, c) __builtin_amdgcn_mfma_f32_16x16x32_bf16(a, b, c, 0, 0, 0)

// ---------- kernel 0: transpose+convert weights into wt[192][1024] bf16 ----------
__global__ __launch_bounds__(256) void wtrans_kernel(const float* __restrict__ wk,
                              const float* __restrict__ wq,
                              const float* __restrict__ wv,
                              unsigned short* __restrict__ wt) {
    __shared__ unsigned short ls[64][72];   // [c][k], padded
    const int m = blockIdx.x >> 4, kt = blockIdx.x & 15;
    const float* w = (m == 0) ? wk : (m == 1) ? wq : wv;
    const int tid = threadIdx.x;
    #pragma unroll
    for (int it = 0; it < 4; ++it) {
        int k = it * 16 + (tid >> 4);
        int c = (tid & 15) * 4;
        float4 f = *(const float4*)(w + (size_t)(kt * 64 + k) * 64 + c);
        ls[c][k] = f2bf(f.x); ls[c + 1][k] = f2bf(f.y);
        ls[c + 2][k] = f2bf(f.z); ls[c + 3][k] = f2bf(f.w);
    }
    __syncthreads();
    const int c = tid >> 2, kc = (tid & 3) * 16;
    unsigned short* dst = wt + (size_t)(m * 64 + c) * 1024 + kt * 64 + kc;
    *(uint4*)dst = *(const uint4*)&ls[c][kc];
    *(uint4*)(dst + 8) = *(const uint4*)&ls[c][kc + 8];
}

// ---------- kernel 1: fused QKV projection v7 (round-22, unchanged) ----------
__global__ __launch_bounds__(256) void qkv_kernel(const float* __restrict__ x,
        const unsigned short* __restrict__ wt,
        unsigned short* __restrict__ kh,
        unsigned short* __restrict__ qh,
        unsigned short* __restrict__ vt) {
    __shared__ __attribute__((aligned(16))) char smem[2][28672];   // x bf16 4KB + wt 24KB
    const int tid = threadIdx.x;
    const int wid = tid >> 6, lane = tid & 63;
    const int lq = lane & 15, g = lane >> 4;
    const int rg = wid & 1, cg = wid >> 1;
    const int row0 = blockIdx.x * 32;
    const char* xg = (const char*)x;
    const char* wtg = (const char*)wt;

    f32x4 acc[6] = {};
    float4 xr0, xr1;                       // in-flight x tile (32B/thread)
    const int xrow = tid >> 3;             // 0..31
    const int xcol = (tid & 7) * 32;       // byte offset within 256B f32 row
    const int xw_off = xrow * 128 + ((((tid & 7) * 16)) ^ ((xrow & 7) << 4));

    auto loadX = [&](int k0) {
        const char* p = xg + (size_t)(row0 + xrow) * 4096 + (size_t)k0 * 4 + xcol;
        xr0 = *(const float4*)p;
        xr1 = *(const float4*)(p + 16);
    };
    auto writeX = [&](char* buf) {
        union { unsigned short u[8]; uint4 v; } pk;
        pk.u[0] = f2bf(xr0.x); pk.u[1] = f2bf(xr0.y); pk.u[2] = f2bf(xr0.z); pk.u[3] = f2bf(xr0.w);
        pk.u[4] = f2bf(xr1.x); pk.u[5] = f2bf(xr1.y); pk.u[6] = f2bf(xr1.z); pk.u[7] = f2bf(xr1.w);
        *(uint4*)(buf + xw_off) = pk.v;
    };
    auto stageW = [&](char* buf, int k0) {
        #pragma unroll
        for (int R = 0; R < 6; ++R) {              // wt: 192 rows x 128B = 24KB
            int o = R * 4096 + tid * 16;
            int row = o >> 7, inrow = o & 127;
            int src = inrow ^ ((row & 7) << 4);
            GLOAD16(wtg + ((size_t)row * 2048 + (size_t)k0 * 2 + src), buf + 4096 + o);
        }
    };

    loadX(0);
    stageW(smem[0], 0);
    writeX(smem[0]);
    asm volatile("s_waitcnt vmcnt(0)" ::: "memory");
    __syncthreads();

    const int arow = rg * 16 + lq;
    const int aswz = (arow & 7) << 4;

    for (int t = 0; t < 16; ++t) {
        char* cur = smem[t & 1];
        char* nxt = smem[(t + 1) & 1];
        if (t < 15) {
            stageW(nxt, (t + 1) * 64);     // async into LDS
            loadX((t + 1) * 64);           // to regs; latency hides under compute
        }

        const char* xb = cur;
        const char* wb = cur + 4096;
        bf16x8 a[2];
        #pragma unroll
        for (int ks = 0; ks < 2; ++ks)
            a[ks] = *(const bf16x8*)(xb + arow * 128 + ((ks * 64 + g * 16) ^ aswz));
        #pragma unroll
        for (int j = 0; j < 6; ++j) {
            int row = cg * 96 + j * 16 + lq;
            #pragma unroll
            for (int ks = 0; ks < 2; ++ks) {
                int kb = ks * 64 + g * 16;
                bf16x8 bfrag = *(const bf16x8*)(wb + row * 128 + (kb ^ ((row & 7) << 4)));
                acc[j] = MFMA16(a[ks], bfrag, acc[j]);
            }
        }
        if (t < 15) writeX(nxt);           // convert + publish next x tile
        asm volatile("s_waitcnt vmcnt(0)" ::: "memory");
        __syncthreads();
    }

    // ---- epilogue ----
    #pragma unroll
    for (int j = 0; j < 6; ++j) {
        int col = cg * 96 + j * 16 + lq;
        int m = col >> 6, h = col & 63;
        if (m < 2) {
            #pragma unroll
            for (int r = 0; r < 4; ++r) {
                int grow = row0 + rg * 16 + g * 4 + r;
                float val = acc[j][r];
                if (m == 0) kh[(size_t)grow * H_ + h] = f2bf(val);
                else        qh[(size_t)grow * H_ + h] = f2bf(val * 0.03125f);  // C^-0.5
            }
        }
    }
    // vt: stage 64x32 tile in LDS, store coalesced uint4 (64B/row)
    unsigned short* vls = (unsigned short*)smem[0];   // [64 h][32 t] bf16, 4KB
    if (cg == 1) {
        #pragma unroll
        for (int j = 2; j < 6; ++j) {
            int vcol = j * 16 + lq - 32;              // 0..63
            #pragma unroll
            for (int r = 0; r < 4; ++r) {
                int trow = rg * 16 + g * 4 + r;       // 0..31
                vls[vcol * 32 + trow] = f2bf(acc[j][r]);
            }
        }
    }
    __syncthreads();
    {
        const int h = tid >> 2, ch = tid & 3;
        const int bb = row0 >> 11, tt = row0 & (T_ - 1);
        *(uint4*)(vt + ((size_t)bb * H_ + h) * T_ + tt + ch * 8) =
            *(const uint4*)&vls[h * 32 + ch * 8];
    }
}

// ---------- kernel 2: causal flash attention v8 — T14 reg-staged K/V ----------
// K/V loaded to registers at step start (latency hides under QK^T/softmax/PV),
// published to LDS via ds_write_b128 just before the barrier. No gload_lds,
// no vmcnt(0) drain on the critical path.
__global__ __launch_bounds__(256) void attn_kernel(const unsigned short* __restrict__ kh,
        const unsigned short* __restrict__ qh,
        const unsigned short* __restrict__ vt,
        float* __restrict__ out,
        unsigned short* __restrict__ po, float* __restrict__ pml, int split) {
    __shared__ __attribute__((aligned(16))) char kv[2][16384];   // K 8KB + V 8KB per buf
    __shared__ __attribute__((aligned(16))) char pl[4][2048];    // per-wave P tile [16 q][64 s] bf16
    const int tid = threadIdx.x;
    const int wid = tid >> 6, lane = tid & 63;
    const int lq = lane & 15, g = lane >> 4;

    int b, qt, c, nch;
    if (split) {
        int qtc = blockIdx.x >> 3; b = blockIdx.x & 7;
        qt = 31 - (qtc >> 3); c = qtc & 7;
        nch = (qt + 4) >> 2;          // ceil((qt*64+64)/256)
        if (c >= nch) return;
    } else {
        b = blockIdx.x & 7; qt = 31 - (blockIdx.x >> 3); c = 0; nch = 1;
    }
    const int qw = qt * 64 + wid * 16;
    const int q_glob = qw + lq;
    const int s_end_blk = qt * 64 + 64;
    const int sbeg = c << 8;
    const int send = (split && sbeg + 256 < s_end_blk) ? sbeg + 256 : s_end_blk;
    const int nt = (send - sbeg) >> 6;

    const char* khb = (const char*)kh + (size_t)b * T_ * H_ * 2;
    const char* vtb = (const char*)vt + (size_t)b * H_ * T_ * 2;
    const unsigned short* qhb = qh + (size_t)b * T_ * H_;

    bf16x8 qf0 = *(const bf16x8*)(qhb + (qw + lq) * H_ + g * 8);
    bf16x8 qf1 = *(const bf16x8*)(qhb + (qw + lq) * H_ + 32 + g * 8);

    // T14 reg-staging: same pre-swizzled global addresses as the old gload_lds
    // source; LDS dest byte = ob (linear), layout unchanged.
    uint4 kr[2], vr[2];
    auto loadKV = [&](int s0) {
        #pragma unroll
        for (int R = 0; R < 2; ++R) {
            int ob = R * 4096 + wid * 1024 + lane * 16;
            int row = ob >> 7, src = (ob & 127) ^ ((row & 7) << 4);
            kr[R] = *(const uint4*)(khb + (size_t)(s0 + row) * 128 + src);
            vr[R] = *(const uint4*)(vtb + (size_t)row * 4096 + (size_t)s0 * 2 + src);
        }
    };
    auto writeKV = [&](char* buf) {
        #pragma unroll
        for (int R = 0; R < 2; ++R) {
            int ob = R * 4096 + wid * 1024 + lane * 16;
            *(uint4*)(buf + ob) = kr[R];
            *(uint4*)(buf + 8192 + ob) = vr[R];
        }
    };

    float m_run = -1e30f, l_run = 0.f;
    f32x4 o_acc[4] = {};
    char* pbase = pl[wid];
    const int pswz = (lq & 7) << 4;

    loadKV(sbeg);
    writeKV(kv[0]);
    __syncthreads();

    for (int t = 0; t < nt; ++t) {
        const int s0 = sbeg + t * 64;
        char* cur = kv[t & 1];
        if (t + 1 < nt) loadKV(s0 + 64);       // regs; latency hides under compute
        const bool domask = (s0 + 64 == s_end_blk);   // diagonal step

        // QK^T: sa[st] = K[s0+st*16..+16][:] . Q^T
        f32x4 sa[4];
        __builtin_amdgcn_s_setprio(1);
        #pragma unroll
        for (int st = 0; st < 4; ++st) {
            int row = st * 16 + lq;
            int swz = (row & 7) << 4;
            f32x4 a = {};
            bf16x8 k0 = *(const bf16x8*)(cur + row * 128 + ((g * 16) ^ swz));
            bf16x8 k1 = *(const bf16x8*)(cur + row * 128 + ((64 + g * 16) ^ swz));
            a = MFMA16(k0, qf0, a);
            a = MFMA16(k1, qf1, a);
            sa[st] = a;
        }
        __builtin_amdgcn_s_setprio(0);

        // online softmax (per-lane q = lq; s = s0 + st*16 + g*4 + r)
        float p[4][4];
        float smax = -1e30f;
        #pragma unroll
        for (int st = 0; st < 4; ++st)
            #pragma unroll
            for (int r = 0; r < 4; ++r) {
                float v = sa[st][r];
                if (domask) {
                    int sg = s0 + st * 16 + g * 4 + r;
                    v = (sg <= q_glob) ? v : -1e30f;
                }
                p[st][r] = v;
                smax = fmaxf(smax, v);
            }
        smax = fmaxf(smax, __shfl_xor(smax, 16));
        smax = fmaxf(smax, __shfl_xor(smax, 32));
        const float m_new = fmaxf(m_run, smax);
        const float alpha = __expf(m_run - m_new);
        float lsum = 0.f;
        #pragma unroll
        for (int st = 0; st < 4; ++st)
            #pragma unroll
            for (int r = 0; r < 4; ++r) {
                p[st][r] = __expf(p[st][r] - m_new);
                lsum += p[st][r];
            }
        lsum += __shfl_xor(lsum, 16);
        lsum += __shfl_xor(lsum, 32);
        l_run = l_run * alpha + lsum;
        m_run = m_new;
        #pragma unroll
        for (int hc = 0; hc < 4; ++hc) o_acc[hc] *= alpha;

        // write P (bf16) to per-wave LDS tile, swizzled rows
        #pragma unroll
        for (int st = 0; st < 4; ++st) {
            union { unsigned short u[4]; uint2 d; } pk;
            pk.u[0] = f2bf(p[st][0]); pk.u[1] = f2bf(p[st][1]);
            pk.u[2] = f2bf(p[st][2]); pk.u[3] = f2bf(p[st][3]);
            *(uint2*)(pbase + lq * 128 + ((st * 32 + g * 8) ^ pswz)) = pk.d;
        }

        // PV: o_acc[hc] += V^T[hc*16+lq][s0+ss*32..] . P^T
        __builtin_amdgcn_s_setprio(1);
        #pragma unroll
        for (int hc = 0; hc < 4; ++hc) {
            int row = hc * 16 + lq;
            int swz = (row & 7) << 4;
            #pragma unroll
            for (int ss = 0; ss < 2; ++ss) {
                bf16x8 vf = *(const bf16x8*)(cur + 8192 + row * 128 + ((ss * 64 + g * 16) ^ swz));
                bf16x8 pb = *(const bf16x8*)(pbase + lq * 128 + ((ss * 64 + g * 16) ^ pswz));
                o_acc[hc] = MFMA16(vf, pb, o_acc[hc]);
            }
        }
        __builtin_amdgcn_s_setprio(0);

        if (t + 1 < nt) {
            writeKV(kv[(t + 1) & 1]);      // publish next tile (buffer freed at prev barrier)
            __syncthreads();
        }
    }

    if (nch == 1) {
        const float inv_l = 1.0f / l_run;
        float* ob = out + ((size_t)b * T_ + qw + lq) * H_;
        #pragma unroll
        for (int hc = 0; hc < 4; ++hc)
            #pragma unroll
            for (int r = 0; r < 4; ++r)
                ob[hc * 16 + g * 4 + r] = o_acc[hc][r] * inv_l;
    } else {
        const int slot = (b * 32 + qt) * 8 + c;
        unsigned short* poS = po + (size_t)slot * 4096;
        const int row = wid * 16 + lq;
        #pragma unroll
        for (int hc = 0; hc < 4; ++hc)
            #pragma unroll
            for (int r = 0; r < 2; ++r) {
                unsigned lo = f2bf(o_acc[hc][r * 2]);
                unsigned hi = f2bf(o_acc[hc][r * 2 + 1]);
                *(unsigned*)(poS + (size_t)row * 64 + hc * 16 + g * 4 + r * 2) = lo | (hi << 16);
            }
        if (g == 0) {
            pml[slot * 64 + row] = m_run;
            pml[131072 + slot * 64 + row] = l_run;
        }
    }
}

// ---------- kernel 3: combine v2 (round-22, unchanged) ----------
__global__ __launch_bounds__(256) void combine_kernel(const unsigned short* __restrict__ po,
        const float* __restrict__ pml, float* __restrict__ out) {
    const int bq = blockIdx.x >> 4, seg = blockIdx.x & 15;
    const int b = bq / 28, qt = 4 + bq % 28;
    const int nch = (qt + 4) >> 2;               // 2..9
    const int r = seg * 4 + (threadIdx.x >> 6);
    const int h = threadIdx.x & 63;
    const int base_slot = (b * 32 + qt) * 8;

    float mv[9], lv[9], ov[9];
    float m = -1e30f;
    #pragma unroll 9
    for (int cc = 0; cc < 9; ++cc) {
        if (cc < nch) {
            mv[cc] = pml[(base_slot + cc) * 64 + r];
            lv[cc] = pml[131072 + (base_slot + cc) * 64 + r];
            ov[cc] = bf2f(po[(size_t)(base_slot + cc) * 4096 + r * 64 + h]);
            m = fmaxf(m, mv[cc]);
        }
    }
    float lsum = 0.f, osum = 0.f;
    #pragma unroll 9
    for (int cc = 0; cc < 9; ++cc) {
        if (cc < nch) {
            float w = __expf(mv[cc] - m);
            lsum += lv[cc] * w;
            osum += ov[cc] * w;
        }
    }
    out[((size_t)b * T_ + qt * 64 + r) * H_ + h] = osum / lsum;
}

extern "C" void kernel_launch(void* const* d_in, const int* in_sizes, int n_in,
                              void* d_out, int out_size, void* d_ws, size_t ws_size,
                              hipStream_t stream) {
    const float* x  = (const float*)d_in[0];
    const float* wk = (const float*)d_in[1];
    const float* wq = (const float*)d_in[2];
    const float* wv = (const float*)d_in[3];
    float* out = (float*)d_out;

    char* ws = (char*)d_ws;
    unsigned short* kh = (unsigned short*)(ws);                            // 2 MB
    unsigned short* qh = (unsigned short*)(ws + (size_t)2 * 1024 * 1024);  // 2 MB
    unsigned short* vt = (unsigned short*)(ws + (size_t)4 * 1024 * 1024);  // 2 MB
    unsigned short* wt = (unsigned short*)(ws + (size_t)6 * 1024 * 1024);  // 384 KB
    unsigned short* po = (unsigned short*)(ws + (size_t)8 * 1024 * 1024);  // 16 MB (bf16, 2048 slots)
    float* pml = (float*)(ws + (size_t)24 * 1024 * 1024);                  // 1 MB

    const bool split = ws_size >= (size_t)26 * 1024 * 1024;

    wtrans_kernel<<<dim3(48), dim3(256), 0, stream>>>(wk, wq, wv, wt);
    qkv_kernel<<<dim3(512), dim3(256), 0, stream>>>(x, wt, kh, qh, vt);
    attn_kernel<<<dim3(split ? 2048 : 256), dim3(256), 0, stream>>>(kh, qh, vt, out, po, pml, split ? 1 : 0);
    if (split)
        combine_kernel<<<dim3(3584), dim3(256), 0, stream>>>(po, pml, out);
}

// Round 24
// 67.098 us; speedup vs baseline: 1.0213x; 1.0213x over previous
//
#include <hip/hip_runtime.h>
#include <hip/hip_bf16.h>

#define B_ 8
#define T_ 2048
#define C_ 1024
#define H_ 64

typedef __bf16 bf16x8 __attribute__((ext_vector_type(8)));
typedef float f32x4 __attribute__((ext_vector_type(4)));

__device__ __forceinline__ unsigned short f2bf(float f) {
    union { float f; unsigned u; } v; v.f = f;
    unsigned u = v.u;
    u += 0x7fffu + ((u >> 16) & 1u);   // round-to-nearest-even
    return (unsigned short)(u >> 16);
}
__device__ __forceinline__ float bf2f(unsigned short u) {
    union { unsigned u; float f; } v; v.u = ((unsigned)u) << 16; return v.f;
}

#define GLOAD16(g, l) __builtin_amdgcn_global_load_lds( \
    (const __attribute__((address_space(1))) void*)(g), \
    (__attribute__((address_space(3))) void*)(l), 16, 0, 0)

#define MFMA16(a, b, c) __builtin_amdgcn_mfma_f32_16x16x32_bf16(a, b, c, 0, 0, 0)

// ---------- kernel 0: transpose+convert weights into wt[192][1024] bf16 ----------
__global__ __launch_bounds__(256) void wtrans_kernel(const float* __restrict__ wk,
                              const float* __restrict__ wq,
                              const float* __restrict__ wv,
                              unsigned short* __restrict__ wt) {
    __shared__ unsigned short ls[64][72];   // [c][k], padded
    const int m = blockIdx.x >> 4, kt = blockIdx.x & 15;
    const float* w = (m == 0) ? wk : (m == 1) ? wq : wv;
    const int tid = threadIdx.x;
    #pragma unroll
    for (int it = 0; it < 4; ++it) {
        int k = it * 16 + (tid >> 4);
        int c = (tid & 15) * 4;
        float4 f = *(const float4*)(w + (size_t)(kt * 64 + k) * 64 + c);
        ls[c][k] = f2bf(f.x); ls[c + 1][k] = f2bf(f.y);
        ls[c + 2][k] = f2bf(f.z); ls[c + 3][k] = f2bf(f.w);
    }
    __syncthreads();
    const int c = tid >> 2, kc = (tid & 3) * 16;
    unsigned short* dst = wt + (size_t)(m * 64 + c) * 1024 + kt * 64 + kc;
    *(uint4*)dst = *(const uint4*)&ls[c][kc];
    *(uint4*)(dst + 8) = *(const uint4*)&ls[c][kc + 8];
}

// ---------- kernel 1: fused QKV projection v7 (round-22, unchanged) ----------
__global__ __launch_bounds__(256) void qkv_kernel(const float* __restrict__ x,
        const unsigned short* __restrict__ wt,
        unsigned short* __restrict__ kh,
        unsigned short* __restrict__ qh,
        unsigned short* __restrict__ vt) {
    __shared__ __attribute__((aligned(16))) char smem[2][28672];   // x bf16 4KB + wt 24KB
    const int tid = threadIdx.x;
    const int wid = tid >> 6, lane = tid & 63;
    const int lq = lane & 15, g = lane >> 4;
    const int rg = wid & 1, cg = wid >> 1;
    const int row0 = blockIdx.x * 32;
    const char* xg = (const char*)x;
    const char* wtg = (const char*)wt;

    f32x4 acc[6] = {};
    float4 xr0, xr1;                       // in-flight x tile (32B/thread)
    const int xrow = tid >> 3;             // 0..31
    const int xcol = (tid & 7) * 32;       // byte offset within 256B f32 row
    const int xw_off = xrow * 128 + ((((tid & 7) * 16)) ^ ((xrow & 7) << 4));

    auto loadX = [&](int k0) {
        const char* p = xg + (size_t)(row0 + xrow) * 4096 + (size_t)k0 * 4 + xcol;
        xr0 = *(const float4*)p;
        xr1 = *(const float4*)(p + 16);
    };
    auto writeX = [&](char* buf) {
        union { unsigned short u[8]; uint4 v; } pk;
        pk.u[0] = f2bf(xr0.x); pk.u[1] = f2bf(xr0.y); pk.u[2] = f2bf(xr0.z); pk.u[3] = f2bf(xr0.w);
        pk.u[4] = f2bf(xr1.x); pk.u[5] = f2bf(xr1.y); pk.u[6] = f2bf(xr1.z); pk.u[7] = f2bf(xr1.w);
        *(uint4*)(buf + xw_off) = pk.v;
    };
    auto stageW = [&](char* buf, int k0) {
        #pragma unroll
        for (int R = 0; R < 6; ++R) {              // wt: 192 rows x 128B = 24KB
            int o = R * 4096 + tid * 16;
            int row = o >> 7, inrow = o & 127;
            int src = inrow ^ ((row & 7) << 4);
            GLOAD16(wtg + ((size_t)row * 2048 + (size_t)k0 * 2 + src), buf + 4096 + o);
        }
    };

    loadX(0);
    stageW(smem[0], 0);
    writeX(smem[0]);
    asm volatile("s_waitcnt vmcnt(0)" ::: "memory");
    __syncthreads();

    const int arow = rg * 16 + lq;
    const int aswz = (arow & 7) << 4;

    for (int t = 0; t < 16; ++t) {
        char* cur = smem[t & 1];
        char* nxt = smem[(t + 1) & 1];
        if (t < 15) {
            stageW(nxt, (t + 1) * 64);     // async into LDS
            loadX((t + 1) * 64);           // to regs; latency hides under compute
        }

        const char* xb = cur;
        const char* wb = cur + 4096;
        bf16x8 a[2];
        #pragma unroll
        for (int ks = 0; ks < 2; ++ks)
            a[ks] = *(const bf16x8*)(xb + arow * 128 + ((ks * 64 + g * 16) ^ aswz));
        #pragma unroll
        for (int j = 0; j < 6; ++j) {
            int row = cg * 96 + j * 16 + lq;
            #pragma unroll
            for (int ks = 0; ks < 2; ++ks) {
                int kb = ks * 64 + g * 16;
                bf16x8 bfrag = *(const bf16x8*)(wb + row * 128 + (kb ^ ((row & 7) << 4)));
                acc[j] = MFMA16(a[ks], bfrag, acc[j]);
            }
        }
        if (t < 15) writeX(nxt);           // convert + publish next x tile
        asm volatile("s_waitcnt vmcnt(0)" ::: "memory");
        __syncthreads();
    }

    // ---- epilogue ----
    #pragma unroll
    for (int j = 0; j < 6; ++j) {
        int col = cg * 96 + j * 16 + lq;
        int m = col >> 6, h = col & 63;
        if (m < 2) {
            #pragma unroll
            for (int r = 0; r < 4; ++r) {
                int grow = row0 + rg * 16 + g * 4 + r;
                float val = acc[j][r];
                if (m == 0) kh[(size_t)grow * H_ + h] = f2bf(val);
                else        qh[(size_t)grow * H_ + h] = f2bf(val * 0.03125f);  // C^-0.5
            }
        }
    }
    // vt: stage 64x32 tile in LDS, store coalesced uint4 (64B/row)
    unsigned short* vls = (unsigned short*)smem[0];   // [64 h][32 t] bf16, 4KB
    if (cg == 1) {
        #pragma unroll
        for (int j = 2; j < 6; ++j) {
            int vcol = j * 16 + lq - 32;              // 0..63
            #pragma unroll
            for (int r = 0; r < 4; ++r) {
                int trow = rg * 16 + g * 4 + r;       // 0..31
                vls[vcol * 32 + trow] = f2bf(acc[j][r]);
            }
        }
    }
    __syncthreads();
    {
        const int h = tid >> 2, ch = tid & 3;
        const int bb = row0 >> 11, tt = row0 & (T_ - 1);
        *(uint4*)(vt + ((size_t)bb * H_ + h) * T_ + tt + ch * 8) =
            *(const uint4*)&vls[h * 32 + ch * 8];
    }
}

// ---------- kernel 2: causal flash attention v8b — T14 reg-staged K/V, pinned ----------
// Prefetch is UNCONDITIONAL (clamped safe address; unused on last step) so the
// branch can't merge with the conditional writeKV; sched_barrier(0) pins load
// issue at step start. vmcnt wait lands only before writeKV at step end.
__global__ __launch_bounds__(256) void attn_kernel(const unsigned short* __restrict__ kh,
        const unsigned short* __restrict__ qh,
        const unsigned short* __restrict__ vt,
        float* __restrict__ out,
        unsigned short* __restrict__ po, float* __restrict__ pml, int split) {
    __shared__ __attribute__((aligned(16))) char kv[2][16384];   // K 8KB + V 8KB per buf
    __shared__ __attribute__((aligned(16))) char pl[4][2048];    // per-wave P tile [16 q][64 s] bf16
    const int tid = threadIdx.x;
    const int wid = tid >> 6, lane = tid & 63;
    const int lq = lane & 15, g = lane >> 4;

    int b, qt, c, nch;
    if (split) {
        int qtc = blockIdx.x >> 3; b = blockIdx.x & 7;
        qt = 31 - (qtc >> 3); c = qtc & 7;
        nch = (qt + 4) >> 2;          // ceil((qt*64+64)/256)
        if (c >= nch) return;
    } else {
        b = blockIdx.x & 7; qt = 31 - (blockIdx.x >> 3); c = 0; nch = 1;
    }
    const int qw = qt * 64 + wid * 16;
    const int q_glob = qw + lq;
    const int s_end_blk = qt * 64 + 64;
    const int sbeg = c << 8;
    const int send = (split && sbeg + 256 < s_end_blk) ? sbeg + 256 : s_end_blk;
    const int nt = (send - sbeg) >> 6;

    const char* khb = (const char*)kh + (size_t)b * T_ * H_ * 2;
    const char* vtb = (const char*)vt + (size_t)b * H_ * T_ * 2;
    const unsigned short* qhb = qh + (size_t)b * T_ * H_;

    bf16x8 qf0 = *(const bf16x8*)(qhb + (qw + lq) * H_ + g * 8);
    bf16x8 qf1 = *(const bf16x8*)(qhb + (qw + lq) * H_ + 32 + g * 8);

    // T14 reg-staging (pre-swizzled global src; linear LDS dest, layout unchanged)
    uint4 kr[2], vr[2];
    auto loadKV = [&](int s0) {
        #pragma unroll
        for (int R = 0; R < 2; ++R) {
            int ob = R * 4096 + wid * 1024 + lane * 16;
            int row = ob >> 7, src = (ob & 127) ^ ((row & 7) << 4);
            kr[R] = *(const uint4*)(khb + (size_t)(s0 + row) * 128 + src);
            vr[R] = *(const uint4*)(vtb + (size_t)row * 4096 + (size_t)s0 * 2 + src);
        }
    };
    auto writeKV = [&](char* buf) {
        #pragma unroll
        for (int R = 0; R < 2; ++R) {
            int ob = R * 4096 + wid * 1024 + lane * 16;
            *(uint4*)(buf + ob) = kr[R];
            *(uint4*)(buf + 8192 + ob) = vr[R];
        }
    };

    float m_run = -1e30f, l_run = 0.f;
    f32x4 o_acc[4] = {};
    char* pbase = pl[wid];
    const int pswz = (lq & 7) << 4;

    loadKV(sbeg);
    writeKV(kv[0]);
    __syncthreads();

    for (int t = 0; t < nt; ++t) {
        const int s0 = sbeg + t * 64;
        char* cur = kv[t & 1];
        // unconditional prefetch (clamped); pinned to issue here
        int sn = s0 + 64; if (sn > T_ - 64) sn = 0;
        loadKV(sn);
        __builtin_amdgcn_sched_barrier(0);
        const bool domask = (s0 + 64 == s_end_blk);   // diagonal step

        // QK^T: sa[st] = K[s0+st*16..+16][:] . Q^T
        f32x4 sa[4];
        __builtin_amdgcn_s_setprio(1);
        #pragma unroll
        for (int st = 0; st < 4; ++st) {
            int row = st * 16 + lq;
            int swz = (row & 7) << 4;
            f32x4 a = {};
            bf16x8 k0 = *(const bf16x8*)(cur + row * 128 + ((g * 16) ^ swz));
            bf16x8 k1 = *(const bf16x8*)(cur + row * 128 + ((64 + g * 16) ^ swz));
            a = MFMA16(k0, qf0, a);
            a = MFMA16(k1, qf1, a);
            sa[st] = a;
        }
        __builtin_amdgcn_s_setprio(0);

        // online softmax (per-lane q = lq; s = s0 + st*16 + g*4 + r)
        float p[4][4];
        float smax = -1e30f;
        #pragma unroll
        for (int st = 0; st < 4; ++st)
            #pragma unroll
            for (int r = 0; r < 4; ++r) {
                float v = sa[st][r];
                if (domask) {
                    int sg = s0 + st * 16 + g * 4 + r;
                    v = (sg <= q_glob) ? v : -1e30f;
                }
                p[st][r] = v;
                smax = fmaxf(smax, v);
            }
        smax = fmaxf(smax, __shfl_xor(smax, 16));
        smax = fmaxf(smax, __shfl_xor(smax, 32));
        const float m_new = fmaxf(m_run, smax);
        const float alpha = __expf(m_run - m_new);
        float lsum = 0.f;
        #pragma unroll
        for (int st = 0; st < 4; ++st)
            #pragma unroll
            for (int r = 0; r < 4; ++r) {
                p[st][r] = __expf(p[st][r] - m_new);
                lsum += p[st][r];
            }
        lsum += __shfl_xor(lsum, 16);
        lsum += __shfl_xor(lsum, 32);
        l_run = l_run * alpha + lsum;
        m_run = m_new;
        #pragma unroll
        for (int hc = 0; hc < 4; ++hc) o_acc[hc] *= alpha;

        // write P (bf16) to per-wave LDS tile, swizzled rows
        #pragma unroll
        for (int st = 0; st < 4; ++st) {
            union { unsigned short u[4]; uint2 d; } pk;
            pk.u[0] = f2bf(p[st][0]); pk.u[1] = f2bf(p[st][1]);
            pk.u[2] = f2bf(p[st][2]); pk.u[3] = f2bf(p[st][3]);
            *(uint2*)(pbase + lq * 128 + ((st * 32 + g * 8) ^ pswz)) = pk.d;
        }

        // PV: o_acc[hc] += V^T[hc*16+lq][s0+ss*32..] . P^T
        __builtin_amdgcn_s_setprio(1);
        #pragma unroll
        for (int hc = 0; hc < 4; ++hc) {
            int row = hc * 16 + lq;
            int swz = (row & 7) << 4;
            #pragma unroll
            for (int ss = 0; ss < 2; ++ss) {
                bf16x8 vf = *(const bf16x8*)(cur + 8192 + row * 128 + ((ss * 64 + g * 16) ^ swz));
                bf16x8 pb = *(const bf16x8*)(pbase + lq * 128 + ((ss * 64 + g * 16) ^ pswz));
                o_acc[hc] = MFMA16(vf, pb, o_acc[hc]);
            }
        }
        __builtin_amdgcn_s_setprio(0);

        if (t + 1 < nt) {
            writeKV(kv[(t + 1) & 1]);      // publish next tile (buffer freed at prev barrier)
            __syncthreads();
        }
    }

    if (nch == 1) {
        const float inv_l = 1.0f / l_run;
        float* ob = out + ((size_t)b * T_ + qw + lq) * H_;
        #pragma unroll
        for (int hc = 0; hc < 4; ++hc)
            #pragma unroll
            for (int r = 0; r < 4; ++r)
                ob[hc * 16 + g * 4 + r] = o_acc[hc][r] * inv_l;
    } else {
        const int slot = (b * 32 + qt) * 8 + c;
        unsigned short* poS = po + (size_t)slot * 4096;
        const int row = wid * 16 + lq;
        #pragma unroll
        for (int hc = 0; hc < 4; ++hc)
            #pragma unroll
            for (int r = 0; r < 2; ++r) {
                unsigned lo = f2bf(o_acc[hc][r * 2]);
                unsigned hi = f2bf(o_acc[hc][r * 2 + 1]);
                *(unsigned*)(poS + (size_t)row * 64 + hc * 16 + g * 4 + r * 2) = lo | (hi << 16);
            }
        if (g == 0) {
            pml[slot * 64 + row] = m_run;
            pml[131072 + slot * 64 + row] = l_run;
        }
    }
}

// ---------- kernel 3: combine v2 (round-22, unchanged) ----------
__global__ __launch_bounds__(256) void combine_kernel(const unsigned short* __restrict__ po,
        const float* __restrict__ pml, float* __restrict__ out) {
    const int bq = blockIdx.x >> 4, seg = blockIdx.x & 15;
    const int b = bq / 28, qt = 4 + bq % 28;
    const int nch = (qt + 4) >> 2;               // 2..9
    const int r = seg * 4 + (threadIdx.x >> 6);
    const int h = threadIdx.x & 63;
    const int base_slot = (b * 32 + qt) * 8;

    float mv[9], lv[9], ov[9];
    float m = -1e30f;
    #pragma unroll 9
    for (int cc = 0; cc < 9; ++cc) {
        if (cc < nch) {
            mv[cc] = pml[(base_slot + cc) * 64 + r];
            lv[cc] = pml[131072 + (base_slot + cc) * 64 + r];
            ov[cc] = bf2f(po[(size_t)(base_slot + cc) * 4096 + r * 64 + h]);
            m = fmaxf(m, mv[cc]);
        }
    }
    float lsum = 0.f, osum = 0.f;
    #pragma unroll 9
    for (int cc = 0; cc < 9; ++cc) {
        if (cc < nch) {
            float w = __expf(mv[cc] - m);
            lsum += lv[cc] * w;
            osum += ov[cc] * w;
        }
    }
    out[((size_t)b * T_ + qt * 64 + r) * H_ + h] = osum / lsum;
}

extern "C" void kernel_launch(void* const* d_in, const int* in_sizes, int n_in,
                              void* d_out, int out_size, void* d_ws, size_t ws_size,
                              hipStream_t stream) {
    const float* x  = (const float*)d_in[0];
    const float* wk = (const float*)d_in[1];
    const float* wq = (const float*)d_in[2];
    const float* wv = (const float*)d_in[3];
    float* out = (float*)d_out;

    char* ws = (char*)d_ws;
    unsigned short* kh = (unsigned short*)(ws);                            // 2 MB
    unsigned short* qh = (unsigned short*)(ws + (size_t)2 * 1024 * 1024);  // 2 MB
    unsigned short* vt = (unsigned short*)(ws + (size_t)4 * 1024 * 1024);  // 2 MB
    unsigned short* wt = (unsigned short*)(ws + (size_t)6 * 1024 * 1024);  // 384 KB
    unsigned short* po = (unsigned short*)(ws + (size_t)8 * 1024 * 1024);  // 16 MB (bf16, 2048 slots)
    float* pml = (float*)(ws + (size_t)24 * 1024 * 1024);                  // 1 MB

    const bool split = ws_size >= (size_t)26 * 1024 * 1024;

    wtrans_kernel<<<dim3(48), dim3(256), 0, stream>>>(wk, wq, wv, wt);
    qkv_kernel<<<dim3(512), dim3(256), 0, stream>>>(x, wt, kh, qh, vt);
    attn_kernel<<<dim3(split ? 2048 : 256), dim3(256), 0, stream>>>(kh, qh, vt, out, po, pml, split ? 1 : 0);
    if (split)
        combine_kernel<<<dim3(3584), dim3(256), 0, stream>>>(po, pml, out);
}

// Round 25
// 55.614 us; speedup vs baseline: 1.2322x; 1.2065x over previous
//
#include <hip/hip_runtime.h>
#include <hip/hip_bf16.h>

#define B_ 8
#define T_ 2048
#define C_ 1024
#define H_ 64

typedef __bf16 bf16x8 __attribute__((ext_vector_type(8)));
typedef float f32x4 __attribute__((ext_vector_type(4)));

__device__ __forceinline__ unsigned short f2bf(float f) {
    union { float f; unsigned u; } v; v.f = f;
    unsigned u = v.u;
    u += 0x7fffu + ((u >> 16) & 1u);   // round-to-nearest-even
    return (unsigned short)(u >> 16);
}
__device__ __forceinline__ float bf2f(unsigned short u) {
    union { unsigned u; float f; } v; v.u = ((unsigned)u) << 16; return v.f;
}

#define GLOAD16(g, l) __builtin_amdgcn_global_load_lds( \
    (const __attribute__((address_space(1))) void*)(g), \
    (__attribute__((address_space(3))) void*)(l), 16, 0, 0)

#define MFMA16(a, b, c) __builtin_amdgcn_mfma_f32_16x16x32_bf16(a, b, c, 0, 0, 0)

// ---------- kernel 0: transpose+convert weights into wt[192][1024] bf16 ----------
__global__ __launch_bounds__(256) void wtrans_kernel(const float* __restrict__ wk,
                              const float* __restrict__ wq,
                              const float* __restrict__ wv,
                              unsigned short* __restrict__ wt) {
    __shared__ unsigned short ls[64][72];   // [c][k], padded
    const int m = blockIdx.x >> 4, kt = blockIdx.x & 15;
    const float* w = (m == 0) ? wk : (m == 1) ? wq : wv;
    const int tid = threadIdx.x;
    #pragma unroll
    for (int it = 0; it < 4; ++it) {
        int k = it * 16 + (tid >> 4);
        int c = (tid & 15) * 4;
        float4 f = *(const float4*)(w + (size_t)(kt * 64 + k) * 64 + c);
        ls[c][k] = f2bf(f.x); ls[c + 1][k] = f2bf(f.y);
        ls[c + 2][k] = f2bf(f.z); ls[c + 3][k] = f2bf(f.w);
    }
    __syncthreads();
    const int c = tid >> 2, kc = (tid & 3) * 16;
    unsigned short* dst = wt + (size_t)(m * 64 + c) * 1024 + kt * 64 + kc;
    *(uint4*)dst = *(const uint4*)&ls[c][kc];
    *(uint4*)(dst + 8) = *(const uint4*)&ls[c][kc + 8];
}

// ---------- kernel 1: fused QKV projection v7 (round-22) ----------
__global__ __launch_bounds__(256) void qkv_kernel(const float* __restrict__ x,
        const unsigned short* __restrict__ wt,
        unsigned short* __restrict__ kh,
        unsigned short* __restrict__ qh,
        unsigned short* __restrict__ vt) {
    __shared__ __attribute__((aligned(16))) char smem[2][28672];   // x bf16 4KB + wt 24KB
    const int tid = threadIdx.x;
    const int wid = tid >> 6, lane = tid & 63;
    const int lq = lane & 15, g = lane >> 4;
    const int rg = wid & 1, cg = wid >> 1;
    const int row0 = blockIdx.x * 32;
    const char* xg = (const char*)x;
    const char* wtg = (const char*)wt;

    f32x4 acc[6] = {};
    float4 xr0, xr1;                       // in-flight x tile (32B/thread)
    const int xrow = tid >> 3;             // 0..31
    const int xcol = (tid & 7) * 32;       // byte offset within 256B f32 row
    const int xw_off = xrow * 128 + ((((tid & 7) * 16)) ^ ((xrow & 7) << 4));

    auto loadX = [&](int k0) {
        const char* p = xg + (size_t)(row0 + xrow) * 4096 + (size_t)k0 * 4 + xcol;
        xr0 = *(const float4*)p;
        xr1 = *(const float4*)(p + 16);
    };
    auto writeX = [&](char* buf) {
        union { unsigned short u[8]; uint4 v; } pk;
        pk.u[0] = f2bf(xr0.x); pk.u[1] = f2bf(xr0.y); pk.u[2] = f2bf(xr0.z); pk.u[3] = f2bf(xr0.w);
        pk.u[4] = f2bf(xr1.x); pk.u[5] = f2bf(xr1.y); pk.u[6] = f2bf(xr1.z); pk.u[7] = f2bf(xr1.w);
        *(uint4*)(buf + xw_off) = pk.v;
    };
    auto stageW = [&](char* buf, int k0) {
        #pragma unroll
        for (int R = 0; R < 6; ++R) {              // wt: 192 rows x 128B = 24KB
            int o = R * 4096 + tid * 16;
            int row = o >> 7, inrow = o & 127;
            int src = inrow ^ ((row & 7) << 4);
            GLOAD16(wtg + ((size_t)row * 2048 + (size_t)k0 * 2 + src), buf + 4096 + o);
        }
    };

    loadX(0);
    stageW(smem[0], 0);
    writeX(smem[0]);
    asm volatile("s_waitcnt vmcnt(0)" ::: "memory");
    __syncthreads();

    const int arow = rg * 16 + lq;
    const int aswz = (arow & 7) << 4;

    for (int t = 0; t < 16; ++t) {
        char* cur = smem[t & 1];
        char* nxt = smem[(t + 1) & 1];
        if (t < 15) {
            stageW(nxt, (t + 1) * 64);     // async into LDS
            loadX((t + 1) * 64);           // to regs; latency hides under compute
        }

        const char* xb = cur;
        const char* wb = cur + 4096;
        bf16x8 a[2];
        #pragma unroll
        for (int ks = 0; ks < 2; ++ks)
            a[ks] = *(const bf16x8*)(xb + arow * 128 + ((ks * 64 + g * 16) ^ aswz));
        #pragma unroll
        for (int j = 0; j < 6; ++j) {
            int row = cg * 96 + j * 16 + lq;
            #pragma unroll
            for (int ks = 0; ks < 2; ++ks) {
                int kb = ks * 64 + g * 16;
                bf16x8 bfrag = *(const bf16x8*)(wb + row * 128 + (kb ^ ((row & 7) << 4)));
                acc[j] = MFMA16(a[ks], bfrag, acc[j]);
            }
        }
        if (t < 15) writeX(nxt);           // convert + publish next x tile
        asm volatile("s_waitcnt vmcnt(0)" ::: "memory");
        __syncthreads();
    }

    // ---- epilogue ----
    #pragma unroll
    for (int j = 0; j < 6; ++j) {
        int col = cg * 96 + j * 16 + lq;
        int m = col >> 6, h = col & 63;
        if (m < 2) {
            #pragma unroll
            for (int r = 0; r < 4; ++r) {
                int grow = row0 + rg * 16 + g * 4 + r;
                float val = acc[j][r];
                if (m == 0) kh[(size_t)grow * H_ + h] = f2bf(val);
                else        qh[(size_t)grow * H_ + h] = f2bf(val * 0.03125f);  // C^-0.5
            }
        }
    }
    // vt: stage 64x32 tile in LDS, store coalesced uint4 (64B/row)
    unsigned short* vls = (unsigned short*)smem[0];   // [64 h][32 t] bf16, 4KB
    if (cg == 1) {
        #pragma unroll
        for (int j = 2; j < 6; ++j) {
            int vcol = j * 16 + lq - 32;              // 0..63
            #pragma unroll
            for (int r = 0; r < 4; ++r) {
                int trow = rg * 16 + g * 4 + r;       // 0..31
                vls[vcol * 32 + trow] = f2bf(acc[j][r]);
            }
        }
    }
    __syncthreads();
    {
        const int h = tid >> 2, ch = tid & 3;
        const int bb = row0 >> 11, tt = row0 & (T_ - 1);
        *(uint4*)(vt + ((size_t)bb * H_ + h) * T_ + tt + ch * 8) =
            *(const uint4*)&vls[h * 32 + ch * 8];
    }
}

// ---------- kernel 2: causal flash attention (round-20/22; gload_lds, skip last drain) ----------
__global__ __launch_bounds__(256) void attn_kernel(const unsigned short* __restrict__ kh,
        const unsigned short* __restrict__ qh,
        const unsigned short* __restrict__ vt,
        float* __restrict__ out,
        unsigned short* __restrict__ po, float* __restrict__ pml, int split) {
    __shared__ __attribute__((aligned(16))) char kv[2][16384];   // K 8KB + V 8KB per buf
    __shared__ __attribute__((aligned(16))) char pl[4][2048];    // per-wave P tile [16 q][64 s] bf16
    const int tid = threadIdx.x;
    const int wid = tid >> 6, lane = tid & 63;
    const int lq = lane & 15, g = lane >> 4;

    int b, qt, c, nch;
    if (split) {
        int qtc = blockIdx.x >> 3; b = blockIdx.x & 7;
        qt = 31 - (qtc >> 3); c = qtc & 7;
        nch = (qt + 4) >> 2;          // ceil((qt*64+64)/256)
        if (c >= nch) return;
    } else {
        b = blockIdx.x & 7; qt = 31 - (blockIdx.x >> 3); c = 0; nch = 1;
    }
    const int qw = qt * 64 + wid * 16;
    const int q_glob = qw + lq;
    const int s_end_blk = qt * 64 + 64;
    const int sbeg = c << 8;
    const int send = (split && sbeg + 256 < s_end_blk) ? sbeg + 256 : s_end_blk;
    const int nt = (send - sbeg) >> 6;

    const char* khb = (const char*)kh + (size_t)b * T_ * H_ * 2;
    const char* vtb = (const char*)vt + (size_t)b * H_ * T_ * 2;
    const unsigned short* qhb = qh + (size_t)b * T_ * H_;

    bf16x8 qf0 = *(const bf16x8*)(qhb + (qw + lq) * H_ + g * 8);
    bf16x8 qf1 = *(const bf16x8*)(qhb + (qw + lq) * H_ + 32 + g * 8);

    auto stage = [&](char* buf, int s0) {
        #pragma unroll
        for (int R = 0; R < 2; ++R) {              // K tile: rows = s, 128B each
            int o = R * 4096 + wid * 1024;
            int ob = o + lane * 16;
            int row = ob >> 7, inrow = ob & 127;
            int src = inrow ^ ((row & 7) << 4);
            GLOAD16(khb + (size_t)(s0 + row) * 128 + src, buf + o);
        }
        #pragma unroll
        for (int R = 0; R < 2; ++R) {              // V tile: rows = h, 128B window of vt row
            int o = R * 4096 + wid * 1024;
            int ob = o + lane * 16;
            int row = ob >> 7, inrow = ob & 127;
            int src = inrow ^ ((row & 7) << 4);
            GLOAD16(vtb + (size_t)row * 4096 + (size_t)s0 * 2 + src, buf + 8192 + o);
        }
    };

    float m_run = -1e30f, l_run = 0.f;
    f32x4 o_acc[4] = {};
    char* pbase = pl[wid];
    const int pswz = (lq & 7) << 4;

    stage(kv[0], sbeg);
    asm volatile("s_waitcnt vmcnt(0)" ::: "memory");
    __syncthreads();

    for (int t = 0; t < nt; ++t) {
        const int s0 = sbeg + t * 64;
        char* cur = kv[t & 1];
        if (t + 1 < nt) stage(kv[(t + 1) & 1], s0 + 64);
        const bool domask = (s0 + 64 == s_end_blk);   // diagonal step

        // QK^T: sa[st] = K[s0+st*16..+16][:] . Q^T
        f32x4 sa[4];
        __builtin_amdgcn_s_setprio(1);
        #pragma unroll
        for (int st = 0; st < 4; ++st) {
            int row = st * 16 + lq;
            int swz = (row & 7) << 4;
            f32x4 a = {};
            bf16x8 k0 = *(const bf16x8*)(cur + row * 128 + ((g * 16) ^ swz));
            bf16x8 k1 = *(const bf16x8*)(cur + row * 128 + ((64 + g * 16) ^ swz));
            a = MFMA16(k0, qf0, a);
            a = MFMA16(k1, qf1, a);
            sa[st] = a;
        }
        __builtin_amdgcn_s_setprio(0);

        // online softmax (per-lane q = lq; s = s0 + st*16 + g*4 + r)
        float p[4][4];
        float smax = -1e30f;
        #pragma unroll
        for (int st = 0; st < 4; ++st)
            #pragma unroll
            for (int r = 0; r < 4; ++r) {
                float v = sa[st][r];
                if (domask) {
                    int sg = s0 + st * 16 + g * 4 + r;
                    v = (sg <= q_glob) ? v : -1e30f;
                }
                p[st][r] = v;
                smax = fmaxf(smax, v);
            }
        smax = fmaxf(smax, __shfl_xor(smax, 16));
        smax = fmaxf(smax, __shfl_xor(smax, 32));
        const float m_new = fmaxf(m_run, smax);
        const float alpha = __expf(m_run - m_new);
        float lsum = 0.f;
        #pragma unroll
        for (int st = 0; st < 4; ++st)
            #pragma unroll
            for (int r = 0; r < 4; ++r) {
                p[st][r] = __expf(p[st][r] - m_new);
                lsum += p[st][r];
            }
        lsum += __shfl_xor(lsum, 16);
        lsum += __shfl_xor(lsum, 32);
        l_run = l_run * alpha + lsum;
        m_run = m_new;
        #pragma unroll
        for (int hc = 0; hc < 4; ++hc) o_acc[hc] *= alpha;

        // write P (bf16) to per-wave LDS tile, swizzled rows
        #pragma unroll
        for (int st = 0; st < 4; ++st) {
            union { unsigned short u[4]; uint2 d; } pk;
            pk.u[0] = f2bf(p[st][0]); pk.u[1] = f2bf(p[st][1]);
            pk.u[2] = f2bf(p[st][2]); pk.u[3] = f2bf(p[st][3]);
            *(uint2*)(pbase + lq * 128 + ((st * 32 + g * 8) ^ pswz)) = pk.d;
        }

        // PV: o_acc[hc] += V^T[hc*16+lq][s0+ss*32..] . P^T
        __builtin_amdgcn_s_setprio(1);
        #pragma unroll
        for (int hc = 0; hc < 4; ++hc) {
            int row = hc * 16 + lq;
            int swz = (row & 7) << 4;
            #pragma unroll
            for (int ss = 0; ss < 2; ++ss) {
                bf16x8 vf = *(const bf16x8*)(cur + 8192 + row * 128 + ((ss * 64 + g * 16) ^ swz));
                bf16x8 pb = *(const bf16x8*)(pbase + lq * 128 + ((ss * 64 + g * 16) ^ pswz));
                o_acc[hc] = MFMA16(vf, pb, o_acc[hc]);
            }
        }
        __builtin_amdgcn_s_setprio(0);

        if (t + 1 < nt) {
            asm volatile("s_waitcnt vmcnt(0)" ::: "memory");
            __syncthreads();
        }
    }

    if (nch == 1) {
        const float inv_l = 1.0f / l_run;
        float* ob = out + ((size_t)b * T_ + qw + lq) * H_;
        #pragma unroll
        for (int hc = 0; hc < 4; ++hc)
            #pragma unroll
            for (int r = 0; r < 4; ++r)
                ob[hc * 16 + g * 4 + r] = o_acc[hc][r] * inv_l;
    } else {
        const int slot = (b * 32 + qt) * 8 + c;
        unsigned short* poS = po + (size_t)slot * 4096;
        const int row = wid * 16 + lq;
        #pragma unroll
        for (int hc = 0; hc < 4; ++hc)
            #pragma unroll
            for (int r = 0; r < 2; ++r) {
                unsigned lo = f2bf(o_acc[hc][r * 2]);
                unsigned hi = f2bf(o_acc[hc][r * 2 + 1]);
                *(unsigned*)(poS + (size_t)row * 64 + hc * 16 + g * 4 + r * 2) = lo | (hi << 16);
            }
        if (g == 0) {
            pml[slot * 64 + row] = m_run;
            pml[131072 + slot * 64 + row] = l_run;
        }
    }
}

// ---------- kernel 3: combine v2 (round-22) ----------
__global__ __launch_bounds__(256) void combine_kernel(const unsigned short* __restrict__ po,
        const float* __restrict__ pml, float* __restrict__ out) {
    const int bq = blockIdx.x >> 4, seg = blockIdx.x & 15;
    const int b = bq / 28, qt = 4 + bq % 28;
    const int nch = (qt + 4) >> 2;               // 2..9
    const int r = seg * 4 + (threadIdx.x >> 6);
    const int h = threadIdx.x & 63;
    const int base_slot = (b * 32 + qt) * 8;

    float mv[9], lv[9], ov[9];
    float m = -1e30f;
    #pragma unroll 9
    for (int cc = 0; cc < 9; ++cc) {
        if (cc < nch) {
            mv[cc] = pml[(base_slot + cc) * 64 + r];
            lv[cc] = pml[131072 + (base_slot + cc) * 64 + r];
            ov[cc] = bf2f(po[(size_t)(base_slot + cc) * 4096 + r * 64 + h]);
            m = fmaxf(m, mv[cc]);
        }
    }
    float lsum = 0.f, osum = 0.f;
    #pragma unroll 9
    for (int cc = 0; cc < 9; ++cc) {
        if (cc < nch) {
            float w = __expf(mv[cc] - m);
            lsum += lv[cc] * w;
            osum += ov[cc] * w;
        }
    }
    out[((size_t)b * T_ + qt * 64 + r) * H_ + h] = osum / lsum;
}

extern "C" void kernel_launch(void* const* d_in, const int* in_sizes, int n_in,
                              void* d_out, int out_size, void* d_ws, size_t ws_size,
                              hipStream_t stream) {
    const float* x  = (const float*)d_in[0];
    const float* wk = (const float*)d_in[1];
    const float* wq = (const float*)d_in[2];
    const float* wv = (const float*)d_in[3];
    float* out = (float*)d_out;

    char* ws = (char*)d_ws;
    unsigned short* kh = (unsigned short*)(ws);                            // 2 MB
    unsigned short* qh = (unsigned short*)(ws + (size_t)2 * 1024 * 1024);  // 2 MB
    unsigned short* vt = (unsigned short*)(ws + (size_t)4 * 1024 * 1024);  // 2 MB
    unsigned short* wt = (unsigned short*)(ws + (size_t)6 * 1024 * 1024);  // 384 KB
    unsigned short* po = (unsigned short*)(ws + (size_t)8 * 1024 * 1024);  // 16 MB (bf16, 2048 slots)
    float* pml = (float*)(ws + (size_t)24 * 1024 * 1024);                  // 1 MB

    const bool split = ws_size >= (size_t)26 * 1024 * 1024;

    wtrans_kernel<<<dim3(48), dim3(256), 0, stream>>>(wk, wq, wv, wt);
    qkv_kernel<<<dim3(512), dim3(256), 0, stream>>>(x, wt, kh, qh, vt);
    attn_kernel<<<dim3(split ? 2048 : 256), dim3(256), 0, stream>>>(kh, qh, vt, out, po, pml, split ? 1 : 0);
    if (split)
        combine_kernel<<<dim3(3584), dim3(256), 0, stream>>>(po, pml, out);
}

// Round 26
// 54.334 us; speedup vs baseline: 1.2612x; 1.0236x over previous
//
#include <hip/hip_runtime.h>
#include <hip/hip_bf16.h>

#define B_ 8
#define T_ 2048
#define C_ 1024
#define H_ 64

typedef __bf16 bf16x8 __attribute__((ext_vector_type(8)));
typedef float f32x4 __attribute__((ext_vector_type(4)));

__device__ __forceinline__ unsigned short f2bf(float f) {
    union { float f; unsigned u; } v; v.f = f;
    unsigned u = v.u;
    u += 0x7fffu + ((u >> 16) & 1u);   // round-to-nearest-even
    return (unsigned short)(u >> 16);
}
__device__ __forceinline__ float bf2f(unsigned short u) {
    union { unsigned u; float f; } v; v.u = ((unsigned)u) << 16; return v.f;
}

#define GLOAD16(g, l) __builtin_amdgcn_global_load_lds( \
    (const __attribute__((address_space(1))) void*)(g), \
    (__attribute__((address_space(3))) void*)(l), 16, 0, 0)

#define MFMA16(a, b, c) __builtin_amdgcn_mfma_f32_16x16x32_bf16(a, b, c, 0, 0, 0)

// ---------- kernel 0: transpose+convert weights into wt[192][1024] bf16 ----------
__global__ __launch_bounds__(256) void wtrans_kernel(const float* __restrict__ wk,
                              const float* __restrict__ wq,
                              const float* __restrict__ wv,
                              unsigned short* __restrict__ wt) {
    __shared__ unsigned short ls[64][72];   // [c][k], padded
    const int m = blockIdx.x >> 4, kt = blockIdx.x & 15;
    const float* w = (m == 0) ? wk : (m == 1) ? wq : wv;
    const int tid = threadIdx.x;
    #pragma unroll
    for (int it = 0; it < 4; ++it) {
        int k = it * 16 + (tid >> 4);
        int c = (tid & 15) * 4;
        float4 f = *(const float4*)(w + (size_t)(kt * 64 + k) * 64 + c);
        ls[c][k] = f2bf(f.x); ls[c + 1][k] = f2bf(f.y);
        ls[c + 2][k] = f2bf(f.z); ls[c + 3][k] = f2bf(f.w);
    }
    __syncthreads();
    const int c = tid >> 2, kc = (tid & 3) * 16;
    unsigned short* dst = wt + (size_t)(m * 64 + c) * 1024 + kt * 64 + kc;
    *(uint4*)dst = *(const uint4*)&ls[c][kc];
    *(uint4*)(dst + 8) = *(const uint4*)&ls[c][kc + 8];
}

// ---------- kernel 1: fused QKV projection v7 (round-22/25, unchanged) ----------
__global__ __launch_bounds__(256) void qkv_kernel(const float* __restrict__ x,
        const unsigned short* __restrict__ wt,
        unsigned short* __restrict__ kh,
        unsigned short* __restrict__ qh,
        unsigned short* __restrict__ vt) {
    __shared__ __attribute__((aligned(16))) char smem[2][28672];   // x bf16 4KB + wt 24KB
    const int tid = threadIdx.x;
    const int wid = tid >> 6, lane = tid & 63;
    const int lq = lane & 15, g = lane >> 4;
    const int rg = wid & 1, cg = wid >> 1;
    const int row0 = blockIdx.x * 32;
    const char* xg = (const char*)x;
    const char* wtg = (const char*)wt;

    f32x4 acc[6] = {};
    float4 xr0, xr1;                       // in-flight x tile (32B/thread)
    const int xrow = tid >> 3;             // 0..31
    const int xcol = (tid & 7) * 32;       // byte offset within 256B f32 row
    const int xw_off = xrow * 128 + ((((tid & 7) * 16)) ^ ((xrow & 7) << 4));

    auto loadX = [&](int k0) {
        const char* p = xg + (size_t)(row0 + xrow) * 4096 + (size_t)k0 * 4 + xcol;
        xr0 = *(const float4*)p;
        xr1 = *(const float4*)(p + 16);
    };
    auto writeX = [&](char* buf) {
        union { unsigned short u[8]; uint4 v; } pk;
        pk.u[0] = f2bf(xr0.x); pk.u[1] = f2bf(xr0.y); pk.u[2] = f2bf(xr0.z); pk.u[3] = f2bf(xr0.w);
        pk.u[4] = f2bf(xr1.x); pk.u[5] = f2bf(xr1.y); pk.u[6] = f2bf(xr1.z); pk.u[7] = f2bf(xr1.w);
        *(uint4*)(buf + xw_off) = pk.v;
    };
    auto stageW = [&](char* buf, int k0) {
        #pragma unroll
        for (int R = 0; R < 6; ++R) {              // wt: 192 rows x 128B = 24KB
            int o = R * 4096 + tid * 16;
            int row = o >> 7, inrow = o & 127;
            int src = inrow ^ ((row & 7) << 4);
            GLOAD16(wtg + ((size_t)row * 2048 + (size_t)k0 * 2 + src), buf + 4096 + o);
        }
    };

    loadX(0);
    stageW(smem[0], 0);
    writeX(smem[0]);
    asm volatile("s_waitcnt vmcnt(0)" ::: "memory");
    __syncthreads();

    const int arow = rg * 16 + lq;
    const int aswz = (arow & 7) << 4;

    for (int t = 0; t < 16; ++t) {
        char* cur = smem[t & 1];
        char* nxt = smem[(t + 1) & 1];
        if (t < 15) {
            stageW(nxt, (t + 1) * 64);     // async into LDS
            loadX((t + 1) * 64);           // to regs; latency hides under compute
        }

        const char* xb = cur;
        const char* wb = cur + 4096;
        bf16x8 a[2];
        #pragma unroll
        for (int ks = 0; ks < 2; ++ks)
            a[ks] = *(const bf16x8*)(xb + arow * 128 + ((ks * 64 + g * 16) ^ aswz));
        #pragma unroll
        for (int j = 0; j < 6; ++j) {
            int row = cg * 96 + j * 16 + lq;
            #pragma unroll
            for (int ks = 0; ks < 2; ++ks) {
                int kb = ks * 64 + g * 16;
                bf16x8 bfrag = *(const bf16x8*)(wb + row * 128 + (kb ^ ((row & 7) << 4)));
                acc[j] = MFMA16(a[ks], bfrag, acc[j]);
            }
        }
        if (t < 15) writeX(nxt);           // convert + publish next x tile
        asm volatile("s_waitcnt vmcnt(0)" ::: "memory");
        __syncthreads();
    }

    // ---- epilogue ----
    #pragma unroll
    for (int j = 0; j < 6; ++j) {
        int col = cg * 96 + j * 16 + lq;
        int m = col >> 6, h = col & 63;
        if (m < 2) {
            #pragma unroll
            for (int r = 0; r < 4; ++r) {
                int grow = row0 + rg * 16 + g * 4 + r;
                float val = acc[j][r];
                if (m == 0) kh[(size_t)grow * H_ + h] = f2bf(val);
                else        qh[(size_t)grow * H_ + h] = f2bf(val * 0.03125f);  // C^-0.5
            }
        }
    }
    // vt: stage 64x32 tile in LDS, store coalesced uint4 (64B/row)
    unsigned short* vls = (unsigned short*)smem[0];   // [64 h][32 t] bf16, 4KB
    if (cg == 1) {
        #pragma unroll
        for (int j = 2; j < 6; ++j) {
            int vcol = j * 16 + lq - 32;              // 0..63
            #pragma unroll
            for (int r = 0; r < 4; ++r) {
                int trow = rg * 16 + g * 4 + r;       // 0..31
                vls[vcol * 32 + trow] = f2bf(acc[j][r]);
            }
        }
    }
    __syncthreads();
    {
        const int h = tid >> 2, ch = tid & 3;
        const int bb = row0 >> 11, tt = row0 & (T_ - 1);
        *(uint4*)(vt + ((size_t)bb * H_ + h) * T_ + tt + ch * 8) =
            *(const uint4*)&vls[h * 32 + ch * 8];
    }
}

// ---------- kernel 2: causal flash attention (round-25 inner loop; EXACT 1152-block grid) ----------
// Task decode: per b, 144 tasks = sum over a=0..7 of 4*(a+1); group a starts
// at 2a(a+1); qt = 4a + off/(a+1), c = off%(a+1); heavy (large qt) first.
__global__ __launch_bounds__(256) void attn_kernel(const unsigned short* __restrict__ kh,
        const unsigned short* __restrict__ qh,
        const unsigned short* __restrict__ vt,
        float* __restrict__ out,
        unsigned short* __restrict__ po, float* __restrict__ pml, int split) {
    __shared__ __attribute__((aligned(16))) char kv[2][16384];   // K 8KB + V 8KB per buf
    __shared__ __attribute__((aligned(16))) char pl[4][2048];    // per-wave P tile [16 q][64 s] bf16
    const int tid = threadIdx.x;
    const int wid = tid >> 6, lane = tid & 63;
    const int lq = lane & 15, g = lane >> 4;

    int b, qt, c, nch;
    if (split) {
        b = blockIdx.x & 7;
        int t_ord = 143 - (blockIdx.x >> 3);     // heavy-first
        int a = 0;
        #pragma unroll
        for (int aa = 7; aa >= 1; --aa) { if (t_ord >= 2 * aa * (aa + 1)) { a = aa; break; } }
        int off = t_ord - 2 * a * (a + 1);
        int qo = 0;
        while (off >= (a + 1)) { off -= (a + 1); ++qo; }   // <=3 iters
        qt = 4 * a + qo; c = off; nch = a + 1;
    } else {
        b = blockIdx.x & 7; qt = 31 - (blockIdx.x >> 3); c = 0; nch = 1;
    }
    const int qw = qt * 64 + wid * 16;
    const int q_glob = qw + lq;
    const int s_end_blk = qt * 64 + 64;
    const int sbeg = c << 8;
    const int send = (split && sbeg + 256 < s_end_blk) ? sbeg + 256 : s_end_blk;
    const int nt = (send - sbeg) >> 6;

    const char* khb = (const char*)kh + (size_t)b * T_ * H_ * 2;
    const char* vtb = (const char*)vt + (size_t)b * H_ * T_ * 2;
    const unsigned short* qhb = qh + (size_t)b * T_ * H_;

    bf16x8 qf0 = *(const bf16x8*)(qhb + (qw + lq) * H_ + g * 8);
    bf16x8 qf1 = *(const bf16x8*)(qhb + (qw + lq) * H_ + 32 + g * 8);

    auto stage = [&](char* buf, int s0) {
        #pragma unroll
        for (int R = 0; R < 2; ++R) {              // K tile: rows = s, 128B each
            int o = R * 4096 + wid * 1024;
            int ob = o + lane * 16;
            int row = ob >> 7, inrow = ob & 127;
            int src = inrow ^ ((row & 7) << 4);
            GLOAD16(khb + (size_t)(s0 + row) * 128 + src, buf + o);
        }
        #pragma unroll
        for (int R = 0; R < 2; ++R) {              // V tile: rows = h, 128B window of vt row
            int o = R * 4096 + wid * 1024;
            int ob = o + lane * 16;
            int row = ob >> 7, inrow = ob & 127;
            int src = inrow ^ ((row & 7) << 4);
            GLOAD16(vtb + (size_t)row * 4096 + (size_t)s0 * 2 + src, buf + 8192 + o);
        }
    };

    float m_run = -1e30f, l_run = 0.f;
    f32x4 o_acc[4] = {};
    char* pbase = pl[wid];
    const int pswz = (lq & 7) << 4;

    stage(kv[0], sbeg);
    asm volatile("s_waitcnt vmcnt(0)" ::: "memory");
    __syncthreads();

    for (int t = 0; t < nt; ++t) {
        const int s0 = sbeg + t * 64;
        char* cur = kv[t & 1];
        if (t + 1 < nt) stage(kv[(t + 1) & 1], s0 + 64);
        const bool domask = (s0 + 64 == s_end_blk);   // diagonal step

        // QK^T: sa[st] = K[s0+st*16..+16][:] . Q^T
        f32x4 sa[4];
        __builtin_amdgcn_s_setprio(1);
        #pragma unroll
        for (int st = 0; st < 4; ++st) {
            int row = st * 16 + lq;
            int swz = (row & 7) << 4;
            f32x4 a = {};
            bf16x8 k0 = *(const bf16x8*)(cur + row * 128 + ((g * 16) ^ swz));
            bf16x8 k1 = *(const bf16x8*)(cur + row * 128 + ((64 + g * 16) ^ swz));
            a = MFMA16(k0, qf0, a);
            a = MFMA16(k1, qf1, a);
            sa[st] = a;
        }
        __builtin_amdgcn_s_setprio(0);

        // online softmax (per-lane q = lq; s = s0 + st*16 + g*4 + r)
        float p[4][4];
        float smax = -1e30f;
        #pragma unroll
        for (int st = 0; st < 4; ++st)
            #pragma unroll
            for (int r = 0; r < 4; ++r) {
                float v = sa[st][r];
                if (domask) {
                    int sg = s0 + st * 16 + g * 4 + r;
                    v = (sg <= q_glob) ? v : -1e30f;
                }
                p[st][r] = v;
                smax = fmaxf(smax, v);
            }
        smax = fmaxf(smax, __shfl_xor(smax, 16));
        smax = fmaxf(smax, __shfl_xor(smax, 32));
        const float m_new = fmaxf(m_run, smax);
        const float alpha = __expf(m_run - m_new);
        float lsum = 0.f;
        #pragma unroll
        for (int st = 0; st < 4; ++st)
            #pragma unroll
            for (int r = 0; r < 4; ++r) {
                p[st][r] = __expf(p[st][r] - m_new);
                lsum += p[st][r];
            }
        lsum += __shfl_xor(lsum, 16);
        lsum += __shfl_xor(lsum, 32);
        l_run = l_run * alpha + lsum;
        m_run = m_new;
        #pragma unroll
        for (int hc = 0; hc < 4; ++hc) o_acc[hc] *= alpha;

        // write P (bf16) to per-wave LDS tile, swizzled rows
        #pragma unroll
        for (int st = 0; st < 4; ++st) {
            union { unsigned short u[4]; uint2 d; } pk;
            pk.u[0] = f2bf(p[st][0]); pk.u[1] = f2bf(p[st][1]);
            pk.u[2] = f2bf(p[st][2]); pk.u[3] = f2bf(p[st][3]);
            *(uint2*)(pbase + lq * 128 + ((st * 32 + g * 8) ^ pswz)) = pk.d;
        }

        // PV: o_acc[hc] += V^T[hc*16+lq][s0+ss*32..] . P^T
        __builtin_amdgcn_s_setprio(1);
        #pragma unroll
        for (int hc = 0; hc < 4; ++hc) {
            int row = hc * 16 + lq;
            int swz = (row & 7) << 4;
            #pragma unroll
            for (int ss = 0; ss < 2; ++ss) {
                bf16x8 vf = *(const bf16x8*)(cur + 8192 + row * 128 + ((ss * 64 + g * 16) ^ swz));
                bf16x8 pb = *(const bf16x8*)(pbase + lq * 128 + ((ss * 64 + g * 16) ^ pswz));
                o_acc[hc] = MFMA16(vf, pb, o_acc[hc]);
            }
        }
        __builtin_amdgcn_s_setprio(0);

        if (t + 1 < nt) {
            asm volatile("s_waitcnt vmcnt(0)" ::: "memory");
            __syncthreads();
        }
    }

    if (nch == 1) {
        const float inv_l = 1.0f / l_run;
        float* ob = out + ((size_t)b * T_ + qw + lq) * H_;
        #pragma unroll
        for (int hc = 0; hc < 4; ++hc)
            #pragma unroll
            for (int r = 0; r < 4; ++r)
                ob[hc * 16 + g * 4 + r] = o_acc[hc][r] * inv_l;
    } else {
        const int slot = (b * 32 + qt) * 8 + c;
        unsigned short* poS = po + (size_t)slot * 4096;
        const int row = wid * 16 + lq;
        #pragma unroll
        for (int hc = 0; hc < 4; ++hc)
            #pragma unroll
            for (int r = 0; r < 2; ++r) {
                unsigned lo = f2bf(o_acc[hc][r * 2]);
                unsigned hi = f2bf(o_acc[hc][r * 2 + 1]);
                *(unsigned*)(poS + (size_t)row * 64 + hc * 16 + g * 4 + r * 2) = lo | (hi << 16);
            }
        if (g == 0) {
            pml[slot * 64 + row] = m_run;
            pml[131072 + slot * 64 + row] = l_run;
        }
    }
}

// ---------- kernel 3: combine v2 (round-25, unchanged) ----------
__global__ __launch_bounds__(256) void combine_kernel(const unsigned short* __restrict__ po,
        const float* __restrict__ pml, float* __restrict__ out) {
    const int bq = blockIdx.x >> 4, seg = blockIdx.x & 15;
    const int b = bq / 28, qt = 4 + bq % 28;
    const int nch = (qt + 4) >> 2;               // 2..9
    const int r = seg * 4 + (threadIdx.x >> 6);
    const int h = threadIdx.x & 63;
    const int base_slot = (b * 32 + qt) * 8;

    float mv[9], lv[9], ov[9];
    float m = -1e30f;
    #pragma unroll 9
    for (int cc = 0; cc < 9; ++cc) {
        if (cc < nch) {
            mv[cc] = pml[(base_slot + cc) * 64 + r];
            lv[cc] = pml[131072 + (base_slot + cc) * 64 + r];
            ov[cc] = bf2f(po[(size_t)(base_slot + cc) * 4096 + r * 64 + h]);
            m = fmaxf(m, mv[cc]);
        }
    }
    float lsum = 0.f, osum = 0.f;
    #pragma unroll 9
    for (int cc = 0; cc < 9; ++cc) {
        if (cc < nch) {
            float w = __expf(mv[cc] - m);
            lsum += lv[cc] * w;
            osum += ov[cc] * w;
        }
    }
    out[((size_t)b * T_ + qt * 64 + r) * H_ + h] = osum / lsum;
}

extern "C" void kernel_launch(void* const* d_in, const int* in_sizes, int n_in,
                              void* d_out, int out_size, void* d_ws, size_t ws_size,
                              hipStream_t stream) {
    const float* x  = (const float*)d_in[0];
    const float* wk = (const float*)d_in[1];
    const float* wq = (const float*)d_in[2];
    const float* wv = (const float*)d_in[3];
    float* out = (float*)d_out;

    char* ws = (char*)d_ws;
    unsigned short* kh = (unsigned short*)(ws);                            // 2 MB
    unsigned short* qh = (unsigned short*)(ws + (size_t)2 * 1024 * 1024);  // 2 MB
    unsigned short* vt = (unsigned short*)(ws + (size_t)4 * 1024 * 1024);  // 2 MB
    unsigned short* wt = (unsigned short*)(ws + (size_t)6 * 1024 * 1024);  // 384 KB
    unsigned short* po = (unsigned short*)(ws + (size_t)8 * 1024 * 1024);  // 16 MB (bf16, 2048 slots)
    float* pml = (float*)(ws + (size_t)24 * 1024 * 1024);                  // 1 MB

    const bool split = ws_size >= (size_t)26 * 1024 * 1024;

    wtrans_kernel<<<dim3(48), dim3(256), 0, stream>>>(wk, wq, wv, wt);
    qkv_kernel<<<dim3(512), dim3(256), 0, stream>>>(x, wt, kh, qh, vt);
    attn_kernel<<<dim3(split ? 1152 : 256), dim3(256), 0, stream>>>(kh, qh, vt, out, po, pml, split ? 1 : 0);
    if (split)
        combine_kernel<<<dim3(3584), dim3(256), 0, stream>>>(po, pml, out);
}

// Round 27
// 53.919 us; speedup vs baseline: 1.2710x; 1.0077x over previous
//
#include <hip/hip_runtime.h>
#include <hip/hip_bf16.h>

#define B_ 8
#define T_ 2048
#define C_ 1024
#define H_ 64

typedef __bf16 bf16x8 __attribute__((ext_vector_type(8)));
typedef float f32x4 __attribute__((ext_vector_type(4)));

__device__ __forceinline__ unsigned short f2bf(float f) {
    union { float f; unsigned u; } v; v.f = f;
    unsigned u = v.u;
    u += 0x7fffu + ((u >> 16) & 1u);   // round-to-nearest-even
    return (unsigned short)(u >> 16);
}
__device__ __forceinline__ float bf2f(unsigned short u) {
    union { unsigned u; float f; } v; v.u = ((unsigned)u) << 16; return v.f;
}

#define GLOAD16(g, l) __builtin_amdgcn_global_load_lds( \
    (const __attribute__((address_space(1))) void*)(g), \
    (__attribute__((address_space(3))) void*)(l), 16, 0, 0)

#define MFMA16(a, b, c) __builtin_amdgcn_mfma_f32_16x16x32_bf16(a, b, c, 0, 0, 0)

// ---------- kernel 0: transpose+convert weights into wt[192][1024] bf16 ----------
__global__ __launch_bounds__(256) void wtrans_kernel(const float* __restrict__ wk,
                              const float* __restrict__ wq,
                              const float* __restrict__ wv,
                              unsigned short* __restrict__ wt) {
    __shared__ unsigned short ls[64][72];   // [c][k], padded
    const int m = blockIdx.x >> 4, kt = blockIdx.x & 15;
    const float* w = (m == 0) ? wk : (m == 1) ? wq : wv;
    const int tid = threadIdx.x;
    #pragma unroll
    for (int it = 0; it < 4; ++it) {
        int k = it * 16 + (tid >> 4);
        int c = (tid & 15) * 4;
        float4 f = *(const float4*)(w + (size_t)(kt * 64 + k) * 64 + c);
        ls[c][k] = f2bf(f.x); ls[c + 1][k] = f2bf(f.y);
        ls[c + 2][k] = f2bf(f.z); ls[c + 3][k] = f2bf(f.w);
    }
    __syncthreads();
    const int c = tid >> 2, kc = (tid & 3) * 16;
    unsigned short* dst = wt + (size_t)(m * 64 + c) * 1024 + kt * 64 + kc;
    *(uint4*)dst = *(const uint4*)&ls[c][kc];
    *(uint4*)(dst + 8) = *(const uint4*)&ls[c][kc + 8];
}

// ---------- kernel 1: fused QKV projection v7 (round-26, unchanged) ----------
__global__ __launch_bounds__(256) void qkv_kernel(const float* __restrict__ x,
        const unsigned short* __restrict__ wt,
        unsigned short* __restrict__ kh,
        unsigned short* __restrict__ qh,
        unsigned short* __restrict__ vt) {
    __shared__ __attribute__((aligned(16))) char smem[2][28672];   // x bf16 4KB + wt 24KB
    const int tid = threadIdx.x;
    const int wid = tid >> 6, lane = tid & 63;
    const int lq = lane & 15, g = lane >> 4;
    const int rg = wid & 1, cg = wid >> 1;
    const int row0 = blockIdx.x * 32;
    const char* xg = (const char*)x;
    const char* wtg = (const char*)wt;

    f32x4 acc[6] = {};
    float4 xr0, xr1;                       // in-flight x tile (32B/thread)
    const int xrow = tid >> 3;             // 0..31
    const int xcol = (tid & 7) * 32;       // byte offset within 256B f32 row
    const int xw_off = xrow * 128 + ((((tid & 7) * 16)) ^ ((xrow & 7) << 4));

    auto loadX = [&](int k0) {
        const char* p = xg + (size_t)(row0 + xrow) * 4096 + (size_t)k0 * 4 + xcol;
        xr0 = *(const float4*)p;
        xr1 = *(const float4*)(p + 16);
    };
    auto writeX = [&](char* buf) {
        union { unsigned short u[8]; uint4 v; } pk;
        pk.u[0] = f2bf(xr0.x); pk.u[1] = f2bf(xr0.y); pk.u[2] = f2bf(xr0.z); pk.u[3] = f2bf(xr0.w);
        pk.u[4] = f2bf(xr1.x); pk.u[5] = f2bf(xr1.y); pk.u[6] = f2bf(xr1.z); pk.u[7] = f2bf(xr1.w);
        *(uint4*)(buf + xw_off) = pk.v;
    };
    auto stageW = [&](char* buf, int k0) {
        #pragma unroll
        for (int R = 0; R < 6; ++R) {              // wt: 192 rows x 128B = 24KB
            int o = R * 4096 + tid * 16;
            int row = o >> 7, inrow = o & 127;
            int src = inrow ^ ((row & 7) << 4);
            GLOAD16(wtg + ((size_t)row * 2048 + (size_t)k0 * 2 + src), buf + 4096 + o);
        }
    };

    loadX(0);
    stageW(smem[0], 0);
    writeX(smem[0]);
    asm volatile("s_waitcnt vmcnt(0)" ::: "memory");
    __syncthreads();

    const int arow = rg * 16 + lq;
    const int aswz = (arow & 7) << 4;

    for (int t = 0; t < 16; ++t) {
        char* cur = smem[t & 1];
        char* nxt = smem[(t + 1) & 1];
        if (t < 15) {
            stageW(nxt, (t + 1) * 64);     // async into LDS
            loadX((t + 1) * 64);           // to regs; latency hides under compute
        }

        const char* xb = cur;
        const char* wb = cur + 4096;
        bf16x8 a[2];
        #pragma unroll
        for (int ks = 0; ks < 2; ++ks)
            a[ks] = *(const bf16x8*)(xb + arow * 128 + ((ks * 64 + g * 16) ^ aswz));
        #pragma unroll
        for (int j = 0; j < 6; ++j) {
            int row = cg * 96 + j * 16 + lq;
            #pragma unroll
            for (int ks = 0; ks < 2; ++ks) {
                int kb = ks * 64 + g * 16;
                bf16x8 bfrag = *(const bf16x8*)(wb + row * 128 + (kb ^ ((row & 7) << 4)));
                acc[j] = MFMA16(a[ks], bfrag, acc[j]);
            }
        }
        if (t < 15) writeX(nxt);           // convert + publish next x tile
        asm volatile("s_waitcnt vmcnt(0)" ::: "memory");
        __syncthreads();
    }

    // ---- epilogue ----
    #pragma unroll
    for (int j = 0; j < 6; ++j) {
        int col = cg * 96 + j * 16 + lq;
        int m = col >> 6, h = col & 63;
        if (m < 2) {
            #pragma unroll
            for (int r = 0; r < 4; ++r) {
                int grow = row0 + rg * 16 + g * 4 + r;
                float val = acc[j][r];
                if (m == 0) kh[(size_t)grow * H_ + h] = f2bf(val);
                else        qh[(size_t)grow * H_ + h] = f2bf(val * 0.03125f);  // C^-0.5
            }
        }
    }
    // vt: stage 64x32 tile in LDS, store coalesced uint4 (64B/row)
    unsigned short* vls = (unsigned short*)smem[0];   // [64 h][32 t] bf16, 4KB
    if (cg == 1) {
        #pragma unroll
        for (int j = 2; j < 6; ++j) {
            int vcol = j * 16 + lq - 32;              // 0..63
            #pragma unroll
            for (int r = 0; r < 4; ++r) {
                int trow = rg * 16 + g * 4 + r;       // 0..31
                vls[vcol * 32 + trow] = f2bf(acc[j][r]);
            }
        }
    }
    __syncthreads();
    {
        const int h = tid >> 2, ch = tid & 3;
        const int bb = row0 >> 11, tt = row0 & (T_ - 1);
        *(uint4*)(vt + ((size_t)bb * H_ + h) * T_ + tt + ch * 8) =
            *(const uint4*)&vls[h * 32 + ch * 8];
    }
}

// ---------- kernel 2: causal flash attention (round-26 grid; setprio REMOVED) ----------
// 4-wave lockstep barrier structure: setprio has no role diversity to exploit
// (T5 prerequisite absent; m190 measured it as a net loss on lockstep kernels).
__global__ __launch_bounds__(256) void attn_kernel(const unsigned short* __restrict__ kh,
        const unsigned short* __restrict__ qh,
        const unsigned short* __restrict__ vt,
        float* __restrict__ out,
        unsigned short* __restrict__ po, float* __restrict__ pml, int split) {
    __shared__ __attribute__((aligned(16))) char kv[2][16384];   // K 8KB + V 8KB per buf
    __shared__ __attribute__((aligned(16))) char pl[4][2048];    // per-wave P tile [16 q][64 s] bf16
    const int tid = threadIdx.x;
    const int wid = tid >> 6, lane = tid & 63;
    const int lq = lane & 15, g = lane >> 4;

    int b, qt, c, nch;
    if (split) {
        b = blockIdx.x & 7;
        int t_ord = 143 - (blockIdx.x >> 3);     // heavy-first
        int a = 0;
        #pragma unroll
        for (int aa = 7; aa >= 1; --aa) { if (t_ord >= 2 * aa * (aa + 1)) { a = aa; break; } }
        int off = t_ord - 2 * a * (a + 1);
        int qo = 0;
        while (off >= (a + 1)) { off -= (a + 1); ++qo; }   // <=3 iters
        qt = 4 * a + qo; c = off; nch = a + 1;
    } else {
        b = blockIdx.x & 7; qt = 31 - (blockIdx.x >> 3); c = 0; nch = 1;
    }
    const int qw = qt * 64 + wid * 16;
    const int q_glob = qw + lq;
    const int s_end_blk = qt * 64 + 64;
    const int sbeg = c << 8;
    const int send = (split && sbeg + 256 < s_end_blk) ? sbeg + 256 : s_end_blk;
    const int nt = (send - sbeg) >> 6;

    const char* khb = (const char*)kh + (size_t)b * T_ * H_ * 2;
    const char* vtb = (const char*)vt + (size_t)b * H_ * T_ * 2;
    const unsigned short* qhb = qh + (size_t)b * T_ * H_;

    bf16x8 qf0 = *(const bf16x8*)(qhb + (qw + lq) * H_ + g * 8);
    bf16x8 qf1 = *(const bf16x8*)(qhb + (qw + lq) * H_ + 32 + g * 8);

    auto stage = [&](char* buf, int s0) {
        #pragma unroll
        for (int R = 0; R < 2; ++R) {              // K tile: rows = s, 128B each
            int o = R * 4096 + wid * 1024;
            int ob = o + lane * 16;
            int row = ob >> 7, inrow = ob & 127;
            int src = inrow ^ ((row & 7) << 4);
            GLOAD16(khb + (size_t)(s0 + row) * 128 + src, buf + o);
        }
        #pragma unroll
        for (int R = 0; R < 2; ++R) {              // V tile: rows = h, 128B window of vt row
            int o = R * 4096 + wid * 1024;
            int ob = o + lane * 16;
            int row = ob >> 7, inrow = ob & 127;
            int src = inrow ^ ((row & 7) << 4);
            GLOAD16(vtb + (size_t)row * 4096 + (size_t)s0 * 2 + src, buf + 8192 + o);
        }
    };

    float m_run = -1e30f, l_run = 0.f;
    f32x4 o_acc[4] = {};
    char* pbase = pl[wid];
    const int pswz = (lq & 7) << 4;

    stage(kv[0], sbeg);
    asm volatile("s_waitcnt vmcnt(0)" ::: "memory");
    __syncthreads();

    for (int t = 0; t < nt; ++t) {
        const int s0 = sbeg + t * 64;
        char* cur = kv[t & 1];
        if (t + 1 < nt) stage(kv[(t + 1) & 1], s0 + 64);
        const bool domask = (s0 + 64 == s_end_blk);   // diagonal step

        // QK^T: sa[st] = K[s0+st*16..+16][:] . Q^T
        f32x4 sa[4];
        #pragma unroll
        for (int st = 0; st < 4; ++st) {
            int row = st * 16 + lq;
            int swz = (row & 7) << 4;
            f32x4 a = {};
            bf16x8 k0 = *(const bf16x8*)(cur + row * 128 + ((g * 16) ^ swz));
            bf16x8 k1 = *(const bf16x8*)(cur + row * 128 + ((64 + g * 16) ^ swz));
            a = MFMA16(k0, qf0, a);
            a = MFMA16(k1, qf1, a);
            sa[st] = a;
        }

        // online softmax (per-lane q = lq; s = s0 + st*16 + g*4 + r)
        float p[4][4];
        float smax = -1e30f;
        #pragma unroll
        for (int st = 0; st < 4; ++st)
            #pragma unroll
            for (int r = 0; r < 4; ++r) {
                float v = sa[st][r];
                if (domask) {
                    int sg = s0 + st * 16 + g * 4 + r;
                    v = (sg <= q_glob) ? v : -1e30f;
                }
                p[st][r] = v;
                smax = fmaxf(smax, v);
            }
        smax = fmaxf(smax, __shfl_xor(smax, 16));
        smax = fmaxf(smax, __shfl_xor(smax, 32));
        const float m_new = fmaxf(m_run, smax);
        const float alpha = __expf(m_run - m_new);
        float lsum = 0.f;
        #pragma unroll
        for (int st = 0; st < 4; ++st)
            #pragma unroll
            for (int r = 0; r < 4; ++r) {
                p[st][r] = __expf(p[st][r] - m_new);
                lsum += p[st][r];
            }
        lsum += __shfl_xor(lsum, 16);
        lsum += __shfl_xor(lsum, 32);
        l_run = l_run * alpha + lsum;
        m_run = m_new;
        #pragma unroll
        for (int hc = 0; hc < 4; ++hc) o_acc[hc] *= alpha;

        // write P (bf16) to per-wave LDS tile, swizzled rows
        #pragma unroll
        for (int st = 0; st < 4; ++st) {
            union { unsigned short u[4]; uint2 d; } pk;
            pk.u[0] = f2bf(p[st][0]); pk.u[1] = f2bf(p[st][1]);
            pk.u[2] = f2bf(p[st][2]); pk.u[3] = f2bf(p[st][3]);
            *(uint2*)(pbase + lq * 128 + ((st * 32 + g * 8) ^ pswz)) = pk.d;
        }

        // PV: o_acc[hc] += V^T[hc*16+lq][s0+ss*32..] . P^T
        #pragma unroll
        for (int hc = 0; hc < 4; ++hc) {
            int row = hc * 16 + lq;
            int swz = (row & 7) << 4;
            #pragma unroll
            for (int ss = 0; ss < 2; ++ss) {
                bf16x8 vf = *(const bf16x8*)(cur + 8192 + row * 128 + ((ss * 64 + g * 16) ^ swz));
                bf16x8 pb = *(const bf16x8*)(pbase + lq * 128 + ((ss * 64 + g * 16) ^ pswz));
                o_acc[hc] = MFMA16(vf, pb, o_acc[hc]);
            }
        }

        if (t + 1 < nt) {
            asm volatile("s_waitcnt vmcnt(0)" ::: "memory");
            __syncthreads();
        }
    }

    if (nch == 1) {
        const float inv_l = 1.0f / l_run;
        float* ob = out + ((size_t)b * T_ + qw + lq) * H_;
        #pragma unroll
        for (int hc = 0; hc < 4; ++hc)
            #pragma unroll
            for (int r = 0; r < 4; ++r)
                ob[hc * 16 + g * 4 + r] = o_acc[hc][r] * inv_l;
    } else {
        const int slot = (b * 32 + qt) * 8 + c;
        unsigned short* poS = po + (size_t)slot * 4096;
        const int row = wid * 16 + lq;
        #pragma unroll
        for (int hc = 0; hc < 4; ++hc)
            #pragma unroll
            for (int r = 0; r < 2; ++r) {
                unsigned lo = f2bf(o_acc[hc][r * 2]);
                unsigned hi = f2bf(o_acc[hc][r * 2 + 1]);
                *(unsigned*)(poS + (size_t)row * 64 + hc * 16 + g * 4 + r * 2) = lo | (hi << 16);
            }
        if (g == 0) {
            pml[slot * 64 + row] = m_run;
            pml[131072 + slot * 64 + row] = l_run;
        }
    }
}

// ---------- kernel 3: combine v2 (round-26, unchanged) ----------
__global__ __launch_bounds__(256) void combine_kernel(const unsigned short* __restrict__ po,
        const float* __restrict__ pml, float* __restrict__ out) {
    const int bq = blockIdx.x >> 4, seg = blockIdx.x & 15;
    const int b = bq / 28, qt = 4 + bq % 28;
    const int nch = (qt + 4) >> 2;               // 2..9
    const int r = seg * 4 + (threadIdx.x >> 6);
    const int h = threadIdx.x & 63;
    const int base_slot = (b * 32 + qt) * 8;

    float mv[9], lv[9], ov[9];
    float m = -1e30f;
    #pragma unroll 9
    for (int cc = 0; cc < 9; ++cc) {
        if (cc < nch) {
            mv[cc] = pml[(base_slot + cc) * 64 + r];
            lv[cc] = pml[131072 + (base_slot + cc) * 64 + r];
            ov[cc] = bf2f(po[(size_t)(base_slot + cc) * 4096 + r * 64 + h]);
            m = fmaxf(m, mv[cc]);
        }
    }
    float lsum = 0.f, osum = 0.f;
    #pragma unroll 9
    for (int cc = 0; cc < 9; ++cc) {
        if (cc < nch) {
            float w = __expf(mv[cc] - m);
            lsum += lv[cc] * w;
            osum += ov[cc] * w;
        }
    }
    out[((size_t)b * T_ + qt * 64 + r) * H_ + h] = osum / lsum;
}

extern "C" void kernel_launch(void* const* d_in, const int* in_sizes, int n_in,
                              void* d_out, int out_size, void* d_ws, size_t ws_size,
                              hipStream_t stream) {
    const float* x  = (const float*)d_in[0];
    const float* wk = (const float*)d_in[1];
    const float* wq = (const float*)d_in[2];
    const float* wv = (const float*)d_in[3];
    float* out = (float*)d_out;

    char* ws = (char*)d_ws;
    unsigned short* kh = (unsigned short*)(ws);                            // 2 MB
    unsigned short* qh = (unsigned short*)(ws + (size_t)2 * 1024 * 1024);  // 2 MB
    unsigned short* vt = (unsigned short*)(ws + (size_t)4 * 1024 * 1024);  // 2 MB
    unsigned short* wt = (unsigned short*)(ws + (size_t)6 * 1024 * 1024);  // 384 KB
    unsigned short* po = (unsigned short*)(ws + (size_t)8 * 1024 * 1024);  // 16 MB (bf16, 2048 slots)
    float* pml = (float*)(ws + (size_t)24 * 1024 * 1024);                  // 1 MB

    const bool split = ws_size >= (size_t)26 * 1024 * 1024;

    wtrans_kernel<<<dim3(48), dim3(256), 0, stream>>>(wk, wq, wv, wt);
    qkv_kernel<<<dim3(512), dim3(256), 0, stream>>>(x, wt, kh, qh, vt);
    attn_kernel<<<dim3(split ? 1152 : 256), dim3(256), 0, stream>>>(kh, qh, vt, out, po, pml, split ? 1 : 0);
    if (split)
        combine_kernel<<<dim3(3584), dim3(256), 0, stream>>>(po, pml, out);
}

// Round 28
// 51.484 us; speedup vs baseline: 1.3311x; 1.0473x over previous
//
#include <hip/hip_runtime.h>
#include <hip/hip_bf16.h>

#define B_ 8
#define T_ 2048
#define C_ 1024
#define H_ 64

typedef __bf16 bf16x8 __attribute__((ext_vector_type(8)));
typedef float f32x4 __attribute__((ext_vector_type(4)));

__device__ __forceinline__ unsigned short f2bf(float f) {
    union { float f; unsigned u; } v; v.f = f;
    unsigned u = v.u;
    u += 0x7fffu + ((u >> 16) & 1u);   // round-to-nearest-even
    return (unsigned short)(u >> 16);
}
__device__ __forceinline__ float bf2f(unsigned short u) {
    union { unsigned u; float f; } v; v.u = ((unsigned)u) << 16; return v.f;
}

#define GLOAD16(g, l) __builtin_amdgcn_global_load_lds( \
    (const __attribute__((address_space(1))) void*)(g), \
    (__attribute__((address_space(3))) void*)(l), 16, 0, 0)

#define MFMA16(a, b, c) __builtin_amdgcn_mfma_f32_16x16x32_bf16(a, b, c, 0, 0, 0)

// ---------- kernel 0: transpose+convert weights into wt[192][1024] bf16 ----------
__global__ __launch_bounds__(256) void wtrans_kernel(const float* __restrict__ wk,
                              const float* __restrict__ wq,
                              const float* __restrict__ wv,
                              unsigned short* __restrict__ wt) {
    __shared__ unsigned short ls[64][72];   // [c][k], padded
    const int m = blockIdx.x >> 4, kt = blockIdx.x & 15;
    const float* w = (m == 0) ? wk : (m == 1) ? wq : wv;
    const int tid = threadIdx.x;
    #pragma unroll
    for (int it = 0; it < 4; ++it) {
        int k = it * 16 + (tid >> 4);
        int c = (tid & 15) * 4;
        float4 f = *(const float4*)(w + (size_t)(kt * 64 + k) * 64 + c);
        ls[c][k] = f2bf(f.x); ls[c + 1][k] = f2bf(f.y);
        ls[c + 2][k] = f2bf(f.z); ls[c + 3][k] = f2bf(f.w);
    }
    __syncthreads();
    const int c = tid >> 2, kc = (tid & 3) * 16;
    unsigned short* dst = wt + (size_t)(m * 64 + c) * 1024 + kt * 64 + kc;
    *(uint4*)dst = *(const uint4*)&ls[c][kc];
    *(uint4*)(dst + 8) = *(const uint4*)&ls[c][kc + 8];
}

// ---------- kernel 1: fused QKV projection v7 (round-26, unchanged) ----------
__global__ __launch_bounds__(256) void qkv_kernel(const float* __restrict__ x,
        const unsigned short* __restrict__ wt,
        unsigned short* __restrict__ kh,
        unsigned short* __restrict__ qh,
        unsigned short* __restrict__ vt) {
    __shared__ __attribute__((aligned(16))) char smem[2][28672];   // x bf16 4KB + wt 24KB
    const int tid = threadIdx.x;
    const int wid = tid >> 6, lane = tid & 63;
    const int lq = lane & 15, g = lane >> 4;
    const int rg = wid & 1, cg = wid >> 1;
    const int row0 = blockIdx.x * 32;
    const char* xg = (const char*)x;
    const char* wtg = (const char*)wt;

    f32x4 acc[6] = {};
    float4 xr0, xr1;                       // in-flight x tile (32B/thread)
    const int xrow = tid >> 3;             // 0..31
    const int xcol = (tid & 7) * 32;       // byte offset within 256B f32 row
    const int xw_off = xrow * 128 + ((((tid & 7) * 16)) ^ ((xrow & 7) << 4));

    auto loadX = [&](int k0) {
        const char* p = xg + (size_t)(row0 + xrow) * 4096 + (size_t)k0 * 4 + xcol;
        xr0 = *(const float4*)p;
        xr1 = *(const float4*)(p + 16);
    };
    auto writeX = [&](char* buf) {
        union { unsigned short u[8]; uint4 v; } pk;
        pk.u[0] = f2bf(xr0.x); pk.u[1] = f2bf(xr0.y); pk.u[2] = f2bf(xr0.z); pk.u[3] = f2bf(xr0.w);
        pk.u[4] = f2bf(xr1.x); pk.u[5] = f2bf(xr1.y); pk.u[6] = f2bf(xr1.z); pk.u[7] = f2bf(xr1.w);
        *(uint4*)(buf + xw_off) = pk.v;
    };
    auto stageW = [&](char* buf, int k0) {
        #pragma unroll
        for (int R = 0; R < 6; ++R) {              // wt: 192 rows x 128B = 24KB
            int o = R * 4096 + tid * 16;
            int row = o >> 7, inrow = o & 127;
            int src = inrow ^ ((row & 7) << 4);
            GLOAD16(wtg + ((size_t)row * 2048 + (size_t)k0 * 2 + src), buf + 4096 + o);
        }
    };

    loadX(0);
    stageW(smem[0], 0);
    writeX(smem[0]);
    asm volatile("s_waitcnt vmcnt(0)" ::: "memory");
    __syncthreads();

    const int arow = rg * 16 + lq;
    const int aswz = (arow & 7) << 4;

    for (int t = 0; t < 16; ++t) {
        char* cur = smem[t & 1];
        char* nxt = smem[(t + 1) & 1];
        if (t < 15) {
            stageW(nxt, (t + 1) * 64);     // async into LDS
            loadX((t + 1) * 64);           // to regs; latency hides under compute
        }

        const char* xb = cur;
        const char* wb = cur + 4096;
        bf16x8 a[2];
        #pragma unroll
        for (int ks = 0; ks < 2; ++ks)
            a[ks] = *(const bf16x8*)(xb + arow * 128 + ((ks * 64 + g * 16) ^ aswz));
        #pragma unroll
        for (int j = 0; j < 6; ++j) {
            int row = cg * 96 + j * 16 + lq;
            #pragma unroll
            for (int ks = 0; ks < 2; ++ks) {
                int kb = ks * 64 + g * 16;
                bf16x8 bfrag = *(const bf16x8*)(wb + row * 128 + (kb ^ ((row & 7) << 4)));
                acc[j] = MFMA16(a[ks], bfrag, acc[j]);
            }
        }
        if (t < 15) writeX(nxt);           // convert + publish next x tile
        asm volatile("s_waitcnt vmcnt(0)" ::: "memory");
        __syncthreads();
    }

    // ---- epilogue ----
    #pragma unroll
    for (int j = 0; j < 6; ++j) {
        int col = cg * 96 + j * 16 + lq;
        int m = col >> 6, h = col & 63;
        if (m < 2) {
            #pragma unroll
            for (int r = 0; r < 4; ++r) {
                int grow = row0 + rg * 16 + g * 4 + r;
                float val = acc[j][r];
                if (m == 0) kh[(size_t)grow * H_ + h] = f2bf(val);
                else        qh[(size_t)grow * H_ + h] = f2bf(val * 0.03125f);  // C^-0.5
            }
        }
    }
    // vt: stage 64x32 tile in LDS, store coalesced uint4 (64B/row)
    unsigned short* vls = (unsigned short*)smem[0];   // [64 h][32 t] bf16, 4KB
    if (cg == 1) {
        #pragma unroll
        for (int j = 2; j < 6; ++j) {
            int vcol = j * 16 + lq - 32;              // 0..63
            #pragma unroll
            for (int r = 0; r < 4; ++r) {
                int trow = rg * 16 + g * 4 + r;       // 0..31
                vls[vcol * 32 + trow] = f2bf(acc[j][r]);
            }
        }
    }
    __syncthreads();
    {
        const int h = tid >> 2, ch = tid & 3;
        const int bb = row0 >> 11, tt = row0 & (T_ - 1);
        *(uint4*)(vt + ((size_t)bb * H_ + h) * T_ + tt + ch * 8) =
            *(const uint4*)&vls[h * 32 + ch * 8];
    }
}

// ---------- kernel 2: causal flash attention (round-27, unchanged) ----------
__global__ __launch_bounds__(256) void attn_kernel(const unsigned short* __restrict__ kh,
        const unsigned short* __restrict__ qh,
        const unsigned short* __restrict__ vt,
        float* __restrict__ out,
        unsigned short* __restrict__ po, float* __restrict__ pml, int split) {
    __shared__ __attribute__((aligned(16))) char kv[2][16384];   // K 8KB + V 8KB per buf
    __shared__ __attribute__((aligned(16))) char pl[4][2048];    // per-wave P tile [16 q][64 s] bf16
    const int tid = threadIdx.x;
    const int wid = tid >> 6, lane = tid & 63;
    const int lq = lane & 15, g = lane >> 4;

    int b, qt, c, nch;
    if (split) {
        b = blockIdx.x & 7;
        int t_ord = 143 - (blockIdx.x >> 3);     // heavy-first
        int a = 0;
        #pragma unroll
        for (int aa = 7; aa >= 1; --aa) { if (t_ord >= 2 * aa * (aa + 1)) { a = aa; break; } }
        int off = t_ord - 2 * a * (a + 1);
        int qo = 0;
        while (off >= (a + 1)) { off -= (a + 1); ++qo; }   // <=3 iters
        qt = 4 * a + qo; c = off; nch = a + 1;
    } else {
        b = blockIdx.x & 7; qt = 31 - (blockIdx.x >> 3); c = 0; nch = 1;
    }
    const int qw = qt * 64 + wid * 16;
    const int q_glob = qw + lq;
    const int s_end_blk = qt * 64 + 64;
    const int sbeg = c << 8;
    const int send = (split && sbeg + 256 < s_end_blk) ? sbeg + 256 : s_end_blk;
    const int nt = (send - sbeg) >> 6;

    const char* khb = (const char*)kh + (size_t)b * T_ * H_ * 2;
    const char* vtb = (const char*)vt + (size_t)b * H_ * T_ * 2;
    const unsigned short* qhb = qh + (size_t)b * T_ * H_;

    bf16x8 qf0 = *(const bf16x8*)(qhb + (qw + lq) * H_ + g * 8);
    bf16x8 qf1 = *(const bf16x8*)(qhb + (qw + lq) * H_ + 32 + g * 8);

    auto stage = [&](char* buf, int s0) {
        #pragma unroll
        for (int R = 0; R < 2; ++R) {              // K tile: rows = s, 128B each
            int o = R * 4096 + wid * 1024;
            int ob = o + lane * 16;
            int row = ob >> 7, inrow = ob & 127;
            int src = inrow ^ ((row & 7) << 4);
            GLOAD16(khb + (size_t)(s0 + row) * 128 + src, buf + o);
        }
        #pragma unroll
        for (int R = 0; R < 2; ++R) {              // V tile: rows = h, 128B window of vt row
            int o = R * 4096 + wid * 1024;
            int ob = o + lane * 16;
            int row = ob >> 7, inrow = ob & 127;
            int src = inrow ^ ((row & 7) << 4);
            GLOAD16(vtb + (size_t)row * 4096 + (size_t)s0 * 2 + src, buf + 8192 + o);
        }
    };

    float m_run = -1e30f, l_run = 0.f;
    f32x4 o_acc[4] = {};
    char* pbase = pl[wid];
    const int pswz = (lq & 7) << 4;

    stage(kv[0], sbeg);
    asm volatile("s_waitcnt vmcnt(0)" ::: "memory");
    __syncthreads();

    for (int t = 0; t < nt; ++t) {
        const int s0 = sbeg + t * 64;
        char* cur = kv[t & 1];
        if (t + 1 < nt) stage(kv[(t + 1) & 1], s0 + 64);
        const bool domask = (s0 + 64 == s_end_blk);   // diagonal step

        // QK^T: sa[st] = K[s0+st*16..+16][:] . Q^T
        f32x4 sa[4];
        #pragma unroll
        for (int st = 0; st < 4; ++st) {
            int row = st * 16 + lq;
            int swz = (row & 7) << 4;
            f32x4 a = {};
            bf16x8 k0 = *(const bf16x8*)(cur + row * 128 + ((g * 16) ^ swz));
            bf16x8 k1 = *(const bf16x8*)(cur + row * 128 + ((64 + g * 16) ^ swz));
            a = MFMA16(k0, qf0, a);
            a = MFMA16(k1, qf1, a);
            sa[st] = a;
        }

        // online softmax (per-lane q = lq; s = s0 + st*16 + g*4 + r)
        float p[4][4];
        float smax = -1e30f;
        #pragma unroll
        for (int st = 0; st < 4; ++st)
            #pragma unroll
            for (int r = 0; r < 4; ++r) {
                float v = sa[st][r];
                if (domask) {
                    int sg = s0 + st * 16 + g * 4 + r;
                    v = (sg <= q_glob) ? v : -1e30f;
                }
                p[st][r] = v;
                smax = fmaxf(smax, v);
            }
        smax = fmaxf(smax, __shfl_xor(smax, 16));
        smax = fmaxf(smax, __shfl_xor(smax, 32));
        const float m_new = fmaxf(m_run, smax);
        const float alpha = __expf(m_run - m_new);
        float lsum = 0.f;
        #pragma unroll
        for (int st = 0; st < 4; ++st)
            #pragma unroll
            for (int r = 0; r < 4; ++r) {
                p[st][r] = __expf(p[st][r] - m_new);
                lsum += p[st][r];
            }
        lsum += __shfl_xor(lsum, 16);
        lsum += __shfl_xor(lsum, 32);
        l_run = l_run * alpha + lsum;
        m_run = m_new;
        #pragma unroll
        for (int hc = 0; hc < 4; ++hc) o_acc[hc] *= alpha;

        // write P (bf16) to per-wave LDS tile, swizzled rows
        #pragma unroll
        for (int st = 0; st < 4; ++st) {
            union { unsigned short u[4]; uint2 d; } pk;
            pk.u[0] = f2bf(p[st][0]); pk.u[1] = f2bf(p[st][1]);
            pk.u[2] = f2bf(p[st][2]); pk.u[3] = f2bf(p[st][3]);
            *(uint2*)(pbase + lq * 128 + ((st * 32 + g * 8) ^ pswz)) = pk.d;
        }

        // PV: o_acc[hc] += V^T[hc*16+lq][s0+ss*32..] . P^T
        #pragma unroll
        for (int hc = 0; hc < 4; ++hc) {
            int row = hc * 16 + lq;
            int swz = (row & 7) << 4;
            #pragma unroll
            for (int ss = 0; ss < 2; ++ss) {
                bf16x8 vf = *(const bf16x8*)(cur + 8192 + row * 128 + ((ss * 64 + g * 16) ^ swz));
                bf16x8 pb = *(const bf16x8*)(pbase + lq * 128 + ((ss * 64 + g * 16) ^ pswz));
                o_acc[hc] = MFMA16(vf, pb, o_acc[hc]);
            }
        }

        if (t + 1 < nt) {
            asm volatile("s_waitcnt vmcnt(0)" ::: "memory");
            __syncthreads();
        }
    }

    if (nch == 1) {
        const float inv_l = 1.0f / l_run;
        float* ob = out + ((size_t)b * T_ + qw + lq) * H_;
        #pragma unroll
        for (int hc = 0; hc < 4; ++hc)
            #pragma unroll
            for (int r = 0; r < 4; ++r)
                ob[hc * 16 + g * 4 + r] = o_acc[hc][r] * inv_l;
    } else {
        const int slot = (b * 32 + qt) * 8 + c;
        unsigned short* poS = po + (size_t)slot * 4096;
        const int row = wid * 16 + lq;
        #pragma unroll
        for (int hc = 0; hc < 4; ++hc)
            #pragma unroll
            for (int r = 0; r < 2; ++r) {
                unsigned lo = f2bf(o_acc[hc][r * 2]);
                unsigned hi = f2bf(o_acc[hc][r * 2 + 1]);
                *(unsigned*)(poS + (size_t)row * 64 + hc * 16 + g * 4 + r * 2) = lo | (hi << 16);
            }
        if (g == 0) {
            pml[slot * 64 + row] = m_run;
            pml[131072 + slot * 64 + row] = l_run;
        }
    }
}

// ---------- kernel 3: combine v3 — 4 outputs/thread, uint2 po reads, float4 stores ----------
// grid: 8 b x 28 qt x 4 seg = 896 blocks; thread -> (row = seg*16 + tid>>4, h0 = (tid&15)*4)
__global__ __launch_bounds__(256) void combine_kernel(const unsigned short* __restrict__ po,
        const float* __restrict__ pml, float* __restrict__ out) {
    const int bq = blockIdx.x >> 2, seg = blockIdx.x & 3;
    const int b = bq / 28, qt = 4 + bq % 28;
    const int nch = (qt + 4) >> 2;               // 2..9
    const int r = seg * 16 + (threadIdx.x >> 4);
    const int h0 = (threadIdx.x & 15) * 4;
    const int base_slot = (b * 32 + qt) * 8;

    float mv[9], lv[9];
    float ov[9][4];
    float m = -1e30f;
    #pragma unroll 9
    for (int cc = 0; cc < 9; ++cc) {
        if (cc < nch) {
            mv[cc] = pml[(base_slot + cc) * 64 + r];
            lv[cc] = pml[131072 + (base_slot + cc) * 64 + r];
            uint2 d = *(const uint2*)(po + (size_t)(base_slot + cc) * 4096 + r * 64 + h0);
            ov[cc][0] = bf2f((unsigned short)(d.x & 0xffff));
            ov[cc][1] = bf2f((unsigned short)(d.x >> 16));
            ov[cc][2] = bf2f((unsigned short)(d.y & 0xffff));
            ov[cc][3] = bf2f((unsigned short)(d.y >> 16));
            m = fmaxf(m, mv[cc]);
        }
    }
    float lsum = 0.f;
    float osum[4] = {0.f, 0.f, 0.f, 0.f};
    #pragma unroll 9
    for (int cc = 0; cc < 9; ++cc) {
        if (cc < nch) {
            float w = __expf(mv[cc] - m);
            lsum += lv[cc] * w;
            #pragma unroll
            for (int i = 0; i < 4; ++i) osum[i] += ov[cc][i] * w;
        }
    }
    const float inv_l = 1.0f / lsum;
    float4 res;
    res.x = osum[0] * inv_l; res.y = osum[1] * inv_l;
    res.z = osum[2] * inv_l; res.w = osum[3] * inv_l;
    *(float4*)(out + ((size_t)b * T_ + qt * 64 + r) * H_ + h0) = res;
}

extern "C" void kernel_launch(void* const* d_in, const int* in_sizes, int n_in,
                              void* d_out, int out_size, void* d_ws, size_t ws_size,
                              hipStream_t stream) {
    const float* x  = (const float*)d_in[0];
    const float* wk = (const float*)d_in[1];
    const float* wq = (const float*)d_in[2];
    const float* wv = (const float*)d_in[3];
    float* out = (float*)d_out;

    char* ws = (char*)d_ws;
    unsigned short* kh = (unsigned short*)(ws);                            // 2 MB
    unsigned short* qh = (unsigned short*)(ws + (size_t)2 * 1024 * 1024);  // 2 MB
    unsigned short* vt = (unsigned short*)(ws + (size_t)4 * 1024 * 1024);  // 2 MB
    unsigned short* wt = (unsigned short*)(ws + (size_t)6 * 1024 * 1024);  // 384 KB
    unsigned short* po = (unsigned short*)(ws + (size_t)8 * 1024 * 1024);  // 16 MB (bf16, 2048 slots)
    float* pml = (float*)(ws + (size_t)24 * 1024 * 1024);                  // 1 MB

    const bool split = ws_size >= (size_t)26 * 1024 * 1024;

    wtrans_kernel<<<dim3(48), dim3(256), 0, stream>>>(wk, wq, wv, wt);
    qkv_kernel<<<dim3(512), dim3(256), 0, stream>>>(x, wt, kh, qh, vt);
    attn_kernel<<<dim3(split ? 1152 : 256), dim3(256), 0, stream>>>(kh, qh, vt, out, po, pml, split ? 1 : 0);
    if (split)
        combine_kernel<<<dim3(896), dim3(256), 0, stream>>>(po, pml, out);
}